// Round 16
// baseline (233.376 us; speedup 1.0000x reference)
//
#include <hip/hip_runtime.h>
#include <hip/hip_bf16.h>

typedef __attribute__((ext_vector_type(4))) float f32x4;
typedef __attribute__((ext_vector_type(16))) float f32x16;
typedef __attribute__((ext_vector_type(8))) short s16x8;
typedef __attribute__((ext_vector_type(4))) short s16x4;
typedef __attribute__((ext_vector_type(2))) short s16x2;

typedef __attribute__((address_space(1))) const unsigned int guint;
typedef __attribute__((address_space(3))) unsigned int luint;

#define D_MODEL 1024
#define NHEAD 16
#define HEAD_DIM 64
#define DFF 4096
#define SEQ 2048
#define BATCH 2
#define QSCALE 0.18033688011112042f   // 0.125 * log2(e); attn uses exp2

__device__ __forceinline__ float b2f(short s) {
  union { unsigned int u; float f; } v;
  v.u = ((unsigned int)(unsigned short)s) << 16;
  return v.f;
}
__device__ __forceinline__ short f2b(float f) {
  __hip_bfloat16 h = __float2bfloat16(f);
  return *reinterpret_cast<short*>(&h);
}
__device__ __forceinline__ s16x8 cvt8(f32x4 a, f32x4 b) {
  s16x8 r;
  #pragma unroll
  for (int i = 0; i < 4; ++i) { r[i] = f2b(a[i]); r[i + 4] = f2b(b[i]); }
  return r;
}

// ---------------------------------------------------------------------------
// FFN GEMM v3: 256x256 tile, BK=64, 512 thr = 8 waves (2m x 4n), per-wave
// 128x64 via 32x32x16 MFMA (acc f32x16[4][2]; higher ceiling 2495 TF, half
// the instruction count of 16x16x32, kk-outer for chain independence).
// LDS 128KB double-buffered, counted vmcnt(2), 2 barriers per K-tile
// (phase-locking measured null r15). 3-bit slot swizzle both sides:
// phys slot = logical ^ (row&7); frag reads land 2 lanes/bank (free).
// A-frag: row = l&31, cols (l>>5)*8 (+kk*16). C: col=lane&31,
// row=(reg&3)+8*(reg>>2)+4*(lane>>5)  [m74/m101 verified map].
// MODE 0: relu(A@W^T+bias) (FFN1). MODE 1: split-K=4, bf16 partials (FFN2).
// ---------------------------------------------------------------------------
template<int MODE>
__global__ __launch_bounds__(512, 2)
void gemm_ff8(const short* __restrict__ A, const short* __restrict__ W,
              const float* __restrict__ bias, short* __restrict__ out,
              int N, int K,
              short* __restrict__ pB, short* __restrict__ pC,
              short* __restrict__ pD)
{
  __shared__ short Al[2][16384];   // 64 KB: [buf][slot(4)*4096 + lin]
  __shared__ short Bl[2][16384];   // 64 KB

  const int tid  = threadIdx.x;
  const int lane = tid & 63, wave = tid >> 6;
  const int l31 = lane & 31, hi = lane >> 5;
  const int wm = (wave >> 2) * 128;      // 0 / 128
  const int wn = (wave & 3) * 64;        // 0..192

  const int nwg = gridDim.x * gridDim.y;
  int lid = blockIdx.y * gridDim.x + blockIdx.x;
  if ((nwg & 7) == 0) lid = (lid & 7) * (nwg >> 3) + (lid >> 3);
  const int bn = lid % gridDim.x, bm = lid / gridDim.x;

  const int Keff = (MODE == 1) ? (K >> 2) : K;
  const int kOff = (MODE == 1) ? (int)blockIdx.z * Keff : 0;

  // staging: thread t covers tile row (slot*64 + t>>3); global col slot
  // pre-swizzled by row&7 = (t>>3)&7 (same 128B line -> coalesced)
  const int srow = tid >> 3;
  const int scol = (((tid & 7) ^ ((tid >> 3) & 7)) * 8);
  const short* gA = A + ((long)(bm * 256) + srow) * K + kOff + scol;
  const short* gW = W + ((long)(bn * 256) + srow) * K + kOff + scol;
  const long slotG = 64L * K;

  auto stage = [&](int buf, int slot, int k0) {
    luint* dA = (luint*)((short*)Al + buf * 16384 + slot * 4096 + wave * 512);
    luint* dB = (luint*)((short*)Bl + buf * 16384 + slot * 4096 + wave * 512);
    __builtin_amdgcn_global_load_lds((guint*)(gA + slot * slotG + k0), dA, 16, 0, 0);
    __builtin_amdgcn_global_load_lds((guint*)(gW + slot * slotG + k0), dB, 16, 0, 0);
  };

  const int sw = l31 & 7;   // row&7 for all frag reads (rows = base + l31)

  f32x16 acc[4][2] = {};

  // prologue: full tile 0 into buf 0 (8 glds per wave)
  #pragma unroll
  for (int s = 0; s < 4; ++s) stage(0, s, 0);

  const int nt = Keff / 64;
  int cur = 0;
  for (int t = 0; t < nt; ++t) {
    const int k1 = (t + 1) * 64;
    if (t + 1 < nt) {
      stage(cur ^ 1, 0, k1);                       // slot 0 early
      asm volatile("s_waitcnt vmcnt(2)" ::: "memory");   // tile t's 8 landed
    } else {
      asm volatile("s_waitcnt vmcnt(0)" ::: "memory");
    }
    __builtin_amdgcn_s_barrier();
    __builtin_amdgcn_sched_barrier(0);

    const short* Abuf = (const short*)Al + cur * 16384;
    const short* Bbuf = (const short*)Bl + cur * 16384;

    #pragma unroll
    for (int p = 0; p < 4; ++p) {
      const int mq = p >> 1, nq = p & 1;

      s16x8 av[2][4], bv4[4];
      #pragma unroll
      for (int mi = 0; mi < 2; ++mi) {
        const int row = wm + (mq * 2 + mi) * 32 + l31;
        #pragma unroll
        for (int kk = 0; kk < 4; ++kk)
          av[mi][kk] = *(const s16x8*)(Abuf + row * 64 + (((kk * 2 + hi) ^ sw) << 3));
      }
      {
        const int row = wn + nq * 32 + l31;
        #pragma unroll
        for (int kk = 0; kk < 4; ++kk)
          bv4[kk] = *(const s16x8*)(Bbuf + row * 64 + (((kk * 2 + hi) ^ sw) << 3));
      }
      if (p > 0 && t + 1 < nt) stage(cur ^ 1, p, k1);

      __builtin_amdgcn_s_setprio(1);
      #pragma unroll
      for (int kk = 0; kk < 4; ++kk)
        #pragma unroll
        for (int mi = 0; mi < 2; ++mi)
          acc[mq * 2 + mi][nq] = __builtin_amdgcn_mfma_f32_32x32x16_bf16(
              av[mi][kk], bv4[kk], acc[mq * 2 + mi][nq], 0, 0, 0);
      __builtin_amdgcn_s_setprio(0);
    }

    __builtin_amdgcn_sched_barrier(0);
    __builtin_amdgcn_s_barrier();   // all reads of buf[cur] done
    cur ^= 1;
  }

  short* oz = out;
  if (MODE == 1) {
    const int z = blockIdx.z;
    oz = (z == 0) ? out : (z == 1) ? pB : (z == 2) ? pC : pD;
  }
  #pragma unroll
  for (int mf = 0; mf < 4; ++mf) {
    #pragma unroll
    for (int nf = 0; nf < 2; ++nf) {
      const int gn = bn * 256 + wn + nf * 32 + l31;
      const float bvv = (MODE == 0) ? bias[gn] : 0.f;
      #pragma unroll
      for (int reg = 0; reg < 16; ++reg) {
        const int gm = bm * 256 + wm + mf * 32 + (reg & 3) + 8 * (reg >> 2) + 4 * hi;
        float v = acc[mf][nf][reg] + bvv;
        if (MODE == 0) v = v > 0.f ? v : 0.f;
        oz[(long)gm * N + gn] = f2b(v);
      }
    }
  }
}

// ---------------------------------------------------------------------------
// NT GEMM (unchanged round-12): 256 thr = 4 waves, tile 128xBN, BK=32,
// counted-vmcnt raw-barrier double-buffer, slot-XOR swizzle, XCD swizzle.
// MODE 0/1; 2/3/4 fallback; 6 split-K; 8 merged QKV.
// ---------------------------------------------------------------------------
template<int MODE, int BN, bool AF32, bool WF32>
__global__ __launch_bounds__(256, 3)
void gemm_nt(const void* __restrict__ Av, const void* __restrict__ Wv,
             const float* __restrict__ bias, short* __restrict__ out,
             int M, int N, int K,
             const int* __restrict__ idx, int R,
             const float* __restrict__ bias2, const float* __restrict__ bias3,
             short* __restrict__ pB, short* __restrict__ pC,
             short* __restrict__ pD)
{
  constexpr bool GLDS = (!AF32 && !WF32);
  constexpr int NI = BN / 32;

  const float* Af = (const float*)Av;
  const short* Ab = (const short*)Av;
  const float* Wf = (const float*)Wv;
  const short* Wb = (const short*)Wv;

  const int tid  = threadIdx.x;
  const int lane = tid & 63, wave = tid >> 6;
  const int g = lane >> 4, l15 = lane & 15;
  const int wm = (wave & 1) * 64, wn = (wave >> 1) * (BN / 2);

  const int nwg = gridDim.x * gridDim.y;
  int lid = blockIdx.y * gridDim.x + blockIdx.x;
  if ((nwg & 7) == 0) lid = (lid & 7) * (nwg >> 3) + (lid >> 3);
  const int bn = lid % gridDim.x;
  const int bm0 = lid / gridDim.x;

  int task = 0, bm = bm0, Mt = M;
  if (MODE == 8) {
    if (bm0 < 32)      { task = 0; bm = bm0;      Mt = M; }
    else if (bm0 < 39) { task = 1; bm = bm0 - 32; Mt = BATCH * R; }
    else               { task = 2; bm = bm0 - 39; Mt = BATCH * R; }
  }

  f32x4 acc[4][NI] = {};

  if constexpr (GLDS) {
    __shared__ short As[2][128][32];
    __shared__ short Bs[2][BN][32];

    const short* Wbase = Wb + ((MODE == 8) ? ((size_t)task << 20) : 0);
    const int nz   = (MODE == 6) ? gridDim.z : 1;
    const int Keff = K / nz;
    const int kOff = (MODE == 6) ? (int)blockIdx.z * Keff : 0;

    const int rA0 = wave * 16 + (lane >> 2);
    const int rA1 = rA0 + 64;
    const int cs = (((lane & 3) ^ ((lane >> 3) & 3)) * 8);

    auto arow = [&](int r) -> long {
      const int gm = bm * 128 + r;
      const int am = gm < Mt ? gm : Mt - 1;
      if (MODE == 8 && task > 0) {
        const int b0 = am / R;
        return (long)(b0 * SEQ + idx[am - b0 * R]);
      }
      return am;
    };
    const long aR0 = arow(rA0), aR1 = arow(rA1);
    const long wR0 = (long)bn * BN + rA0;

    const short* gA0 = Ab + aR0 * K + kOff + cs;
    const short* gA1 = Ab + aR1 * K + kOff + cs;
    const short* gB0 = Wbase + wR0 * K + kOff + cs;
    const short* gB1 = nullptr;
    if constexpr (BN == 128) gB1 = Wbase + ((long)bn * BN + rA1) * K + kOff + cs;

    auto stage = [&](int buf, int k0) {
      luint* lA0 = (luint*)((short*)As + buf * 4096 + wave * 512);
      luint* lA1 = (luint*)((short*)As + buf * 4096 + (4 + wave) * 512);
      luint* lB0 = (luint*)((short*)Bs + buf * (BN * 32) + wave * 512);
      __builtin_amdgcn_global_load_lds((guint*)(gA0 + k0), lA0, 16, 0, 0);
      __builtin_amdgcn_global_load_lds((guint*)(gA1 + k0), lA1, 16, 0, 0);
      __builtin_amdgcn_global_load_lds((guint*)(gB0 + k0), lB0, 16, 0, 0);
      if constexpr (BN == 128) {
        luint* lB1 = (luint*)((short*)Bs + buf * (BN * 32) + (4 + wave) * 512);
        __builtin_amdgcn_global_load_lds((guint*)(gB1 + k0), lB1, 16, 0, 0);
      }
    };

    const int rcol = ((g ^ ((l15 >> 1) & 3)) * 8);

    const int nt = Keff / 32;
    stage(0, 0);
    int cur = 0;
    for (int t = 0; t < nt; ++t) {
      if (t + 1 < nt) {
        stage(cur ^ 1, (t + 1) * 32);
        if constexpr (BN == 128) asm volatile("s_waitcnt vmcnt(4)" ::: "memory");
        else                     asm volatile("s_waitcnt vmcnt(3)" ::: "memory");
      } else {
        asm volatile("s_waitcnt vmcnt(0)" ::: "memory");
      }
      __builtin_amdgcn_s_barrier();
      __builtin_amdgcn_sched_barrier(0);

      s16x8 af[4], bf4[NI];
      #pragma unroll
      for (int mi = 0; mi < 4; ++mi)
        af[mi] = *(const s16x8*)&As[cur][wm + mi * 16 + l15][rcol];
      #pragma unroll
      for (int ni = 0; ni < NI; ++ni)
        bf4[ni] = *(const s16x8*)&Bs[cur][wn + ni * 16 + l15][rcol];
      #pragma unroll
      for (int mi = 0; mi < 4; ++mi)
        #pragma unroll
        for (int ni = 0; ni < NI; ++ni)
          acc[mi][ni] = __builtin_amdgcn_mfma_f32_16x16x32_bf16(af[mi], bf4[ni], acc[mi][ni], 0, 0, 0);

      __builtin_amdgcn_sched_barrier(0);
      __builtin_amdgcn_s_barrier();
      cur ^= 1;
    }
  } else {
    __shared__ short As[128][40];
    __shared__ short Bs[128][40];
    const int r0 = tid >> 1, c0 = (tid & 1) * 16;
    const int gm0 = bm * 128 + r0;
    const int am0 = gm0 < M ? gm0 : M - 1;
    long aRow0;
    if (MODE == 3 || MODE == 4) {
      const int b0 = am0 / R;
      aRow0 = (long)(b0 * SEQ + idx[am0 - b0 * R]);
    } else {
      aRow0 = am0;
    }
    const long wRow0 = bn * 128 + r0;

    for (int k0 = 0; k0 < K; k0 += 32) {
      __syncthreads();
      if (AF32) {
        f32x4 a0 = *(const f32x4*)(Af + aRow0 * K + k0 + c0);
        f32x4 a1 = *(const f32x4*)(Af + aRow0 * K + k0 + c0 + 4);
        f32x4 a2 = *(const f32x4*)(Af + aRow0 * K + k0 + c0 + 8);
        f32x4 a3 = *(const f32x4*)(Af + aRow0 * K + k0 + c0 + 12);
        *(s16x8*)&As[r0][c0]     = cvt8(a0, a1);
        *(s16x8*)&As[r0][c0 + 8] = cvt8(a2, a3);
      } else {
        *(s16x8*)&As[r0][c0]     = *(const s16x8*)(Ab + aRow0 * K + k0 + c0);
        *(s16x8*)&As[r0][c0 + 8] = *(const s16x8*)(Ab + aRow0 * K + k0 + c0 + 8);
      }
      if (WF32) {
        f32x4 w0 = *(const f32x4*)(Wf + wRow0 * K + k0 + c0);
        f32x4 w1 = *(const f32x4*)(Wf + wRow0 * K + k0 + c0 + 4);
        f32x4 w2 = *(const f32x4*)(Wf + wRow0 * K + k0 + c0 + 8);
        f32x4 w3 = *(const f32x4*)(Wf + wRow0 * K + k0 + c0 + 12);
        *(s16x8*)&Bs[r0][c0]     = cvt8(w0, w1);
        *(s16x8*)&Bs[r0][c0 + 8] = cvt8(w2, w3);
      } else {
        *(s16x8*)&Bs[r0][c0]     = *(const s16x8*)(Wb + wRow0 * K + k0 + c0);
        *(s16x8*)&Bs[r0][c0 + 8] = *(const s16x8*)(Wb + wRow0 * K + k0 + c0 + 8);
      }
      __syncthreads();

      s16x8 af[4], bf4[4];
      #pragma unroll
      for (int mi = 0; mi < 4; ++mi)
        af[mi] = *(const s16x8*)&As[wm + mi * 16 + l15][g * 8];
      #pragma unroll
      for (int ni = 0; ni < 4; ++ni)
        bf4[ni] = *(const s16x8*)&Bs[wn + ni * 16 + l15][g * 8];
      #pragma unroll
      for (int mi = 0; mi < 4; ++mi)
        #pragma unroll
        for (int ni = 0; ni < 4; ++ni)
          acc[mi][ni % NI] = __builtin_amdgcn_mfma_f32_16x16x32_bf16(af[mi], bf4[ni], acc[mi][ni % NI], 0, 0, 0);
    }
  }

  short* outz = out;
  if (MODE == 6) {
    const int z = blockIdx.z;
    outz = (z == 0) ? out : (z == 1) ? pB : (z == 2) ? pC : pD;
  }

  #pragma unroll
  for (int mi = 0; mi < 4; ++mi) {
    #pragma unroll
    for (int ni = 0; ni < NI; ++ni) {
      const int gn = bn * BN + wn + ni * 16 + l15;
      float bv;
      if (MODE == 6)      bv = 0.f;
      else if (MODE == 8) bv = (task == 0) ? bias[gn] : (task == 1) ? bias2[gn] : bias3[gn];
      else                bv = bias[gn];
      #pragma unroll
      for (int r = 0; r < 4; ++r) {
        const int gm = bm * 128 + wm + mi * 16 + g * 4 + r;
        if (MODE == 8) { if (gm >= Mt) continue; }
        else           { if (gm >= M)  continue; }
        float v = acc[mi][ni][r] + bv;
        if (MODE == 1) v = v > 0.f ? v : 0.f;
        if (MODE == 2) v *= QSCALE;
        if (MODE == 0 || MODE == 1) {
          out[(long)gm * N + gn] = f2b(v);
        } else if (MODE == 2) {
          const int b = gm >> 11, s = gm & (SEQ - 1);
          const int h = gn >> 6, d = gn & 63;
          out[(((long)(b * NHEAD + h)) * SEQ + s) * 64 + d] = f2b(v);
        } else if (MODE == 3) {
          const int b = gm / R, s = idx[gm - b * R];
          const int h = gn >> 6, d = gn & 63;
          out[(((long)(b * NHEAD + h)) * SEQ + s) * 64 + d] = f2b(v);
        } else if (MODE == 4) {
          const int b = gm / R, s = idx[gm - b * R];
          const int h = gn >> 6, d = gn & 63;
          out[(((long)(b * NHEAD + h)) * 64 + d) * SEQ + s] = f2b(v);
        } else if (MODE == 6) {
          outz[(long)gm * N + gn] = f2b(v);
        } else {  // MODE 8
          const int h = gn >> 6, d = gn & 63;
          if (task == 0) {
            const int b = gm >> 11, s = gm & (SEQ - 1);
            out[(((long)(b * NHEAD + h)) * SEQ + s) * 64 + d] = f2b(v * QSCALE);
          } else if (task == 1) {
            const int b = gm / R, s = idx[gm - b * R];
            (out + (1L << 22))[(((long)(b * NHEAD + h)) * SEQ + s) * 64 + d] = f2b(v);
          } else {
            const int b = gm / R, s = idx[gm - b * R];
            (out + (1L << 23))[(((long)(b * NHEAD + h)) * 64 + d) * SEQ + s] = f2b(v);
          }
        }
      }
    }
  }
}

// ---------------------------------------------------------------------------
// Flash attention fwd v4 (unchanged): swapped QK^T, permlane P, pre-swizzled
// glds staging, exp2, ones-MFMA row-sum, counted-vmcnt raw-barrier loop.
// ---------------------------------------------------------------------------
__global__ __launch_bounds__(256, 2)
void attn_fwd(const short* __restrict__ Q, const short* __restrict__ Kf,
              const short* __restrict__ Vt, short* __restrict__ out)
{
  __shared__ short Kl[2][64][64];
  __shared__ short Vl[2][64][64];

  const int tid  = threadIdx.x;
  const int lane = tid & 63, w = tid >> 6;
  const int g = lane >> 4, l15 = lane & 15;
  const int bh = blockIdx.x;
  const int qt = blockIdx.y;
  const int b  = bh >> 4, h = bh & 15;

  const long base = (long)bh * SEQ * 64;
  const int  q0   = qt * 128 + w * 32;

  s16x8 qf[2][2];
  #pragma unroll
  for (int mi = 0; mi < 2; ++mi)
    #pragma unroll
    for (int c = 0; c < 2; ++c)
      qf[mi][c] = *(const s16x8*)(Q + base + (long)(q0 + mi * 16 + l15) * 64 + c * 32 + g * 8);

  f32x4 o[2][4] = {};
  f32x4 os[2] = {};

  s16x8 ones;
  #pragma unroll
  for (int j = 0; j < 8; ++j) ones[j] = (short)0x3F80;

  auto ldsw = [](short (*buf)[64], int row, int slot) -> short* {
    return (short*)((char*)&buf[0][0] + row * 128 + ((slot ^ (row & 7)) << 4));
  };

  const int bo0 = w * 2048 + lane * 16;
  const int bo1 = bo0 + 1024;
  const int row0 = bo0 >> 7, ss0 = (((bo0 >> 4) & 7) ^ (row0 & 7));
  const int row1 = bo1 >> 7, ss1 = (((bo1 >> 4) & 7) ^ (row1 & 7));
  const short* gK0 = Kf + base + row0 * 64 + ss0 * 8;
  const short* gK1 = Kf + base + row1 * 64 + ss1 * 8;
  const short* gV0 = Vt + base + (long)row0 * SEQ + ss0 * 8;
  const short* gV1 = Vt + base + (long)row1 * SEQ + ss1 * 8;

  auto stage = [&](int buf, int t) {
    char* kb8 = (char*)&Kl[buf][0][0] + w * 2048;
    char* vb8 = (char*)&Vl[buf][0][0] + w * 2048;
    __builtin_amdgcn_global_load_lds((guint*)(gK0 + t * 4096), (luint*)kb8, 16, 0, 0);
    __builtin_amdgcn_global_load_lds((guint*)(gK1 + t * 4096), (luint*)(kb8 + 1024), 16, 0, 0);
    __builtin_amdgcn_global_load_lds((guint*)(gV0 + t * 64), (luint*)vb8, 16, 0, 0);
    __builtin_amdgcn_global_load_lds((guint*)(gV1 + t * 64), (luint*)(vb8 + 1024), 16, 0, 0);
  };

  stage(0, 0);
  int cur = 0;
  for (int t = 0; t < SEQ / 64; ++t) {
    if (t + 1 < SEQ / 64) {
      stage(cur ^ 1, t + 1);
      asm volatile("s_waitcnt vmcnt(4)" ::: "memory");
    } else {
      asm volatile("s_waitcnt vmcnt(0)" ::: "memory");
    }
    __builtin_amdgcn_s_barrier();
    __builtin_amdgcn_sched_barrier(0);

    f32x4 sc[2][4] = {};
    __builtin_amdgcn_s_setprio(1);
    #pragma unroll
    for (int c = 0; c < 2; ++c)
      #pragma unroll
      for (int n = 0; n < 4; ++n) {
        s16x8 kb = *(const s16x8*)ldsw(Kl[cur], n * 16 + l15, c * 4 + g);
        sc[0][n] = __builtin_amdgcn_mfma_f32_16x16x32_bf16(kb, qf[0][c], sc[0][n], 0, 0, 0);
        sc[1][n] = __builtin_amdgcn_mfma_f32_16x16x32_bf16(kb, qf[1][c], sc[1][n], 0, 0, 0);
      }
    __builtin_amdgcn_s_setprio(0);

    s16x8 pa[2][2];
    #pragma unroll
    for (int mi = 0; mi < 2; ++mi) {
      #pragma unroll
      for (int n = 0; n < 4; ++n)
        #pragma unroll
        for (int r = 0; r < 4; ++r) {
          float e;
          asm("v_exp_f32 %0, %1" : "=v"(e) : "v"(sc[mi][n][r]));
          sc[mi][n][r] = e;
        }
      unsigned int wpk[4][2];
      #pragma unroll
      for (int n = 0; n < 4; ++n)
        #pragma unroll
        for (int p = 0; p < 2; ++p)
          asm("v_cvt_pk_bf16_f32 %0, %1, %2"
              : "=v"(wpk[n][p]) : "v"(sc[mi][n][2 * p]), "v"(sc[mi][n][2 * p + 1]));
      #pragma unroll
      for (int c = 0; c < 2; ++c) {
        union { s16x8 v; unsigned int u[4]; } pu;
        #pragma unroll
        for (int p = 0; p < 2; ++p) {
          unsigned int a = wpk[2 * c][p], bb = wpk[2 * c + 1][p];
          asm volatile("v_permlane32_swap_b32 %0, %1" : "+v"(a), "+v"(bb));
          asm volatile("v_permlane16_swap_b32 %0, %1" : "+v"(a), "+v"(bb));
          pu.u[p]     = a;
          pu.u[2 + p] = bb;
        }
        pa[mi][c] = pu.v;
      }
    }

    __builtin_amdgcn_s_setprio(1);
    #pragma unroll
    for (int dt = 0; dt < 4; ++dt)
      #pragma unroll
      for (int c = 0; c < 2; ++c) {
        s16x8 vb = *(const s16x8*)ldsw(Vl[cur], dt * 16 + l15, c * 4 + g);
        o[0][dt] = __builtin_amdgcn_mfma_f32_16x16x32_bf16(pa[0][c], vb, o[0][dt], 0, 0, 0);
        o[1][dt] = __builtin_amdgcn_mfma_f32_16x16x32_bf16(pa[1][c], vb, o[1][dt], 0, 0, 0);
      }
    #pragma unroll
    for (int mi = 0; mi < 2; ++mi)
      #pragma unroll
      for (int c = 0; c < 2; ++c)
        os[mi] = __builtin_amdgcn_mfma_f32_16x16x32_bf16(pa[mi][c], ones, os[mi], 0, 0, 0);
    __builtin_amdgcn_s_setprio(0);

    __builtin_amdgcn_sched_barrier(0);
    __builtin_amdgcn_s_barrier();
    cur ^= 1;
  }

  float inv[2][4];
  #pragma unroll
  for (int mi = 0; mi < 2; ++mi)
    #pragma unroll
    for (int r = 0; r < 4; ++r)
      inv[mi][r] = 1.0f / os[mi][r];

  #pragma unroll
  for (int mi = 0; mi < 2; ++mi)
    #pragma unroll
    for (int dt = 0; dt < 4; ++dt)
      #pragma unroll
      for (int r = 0; r < 4; ++r) {
        const int q   = q0 + mi * 16 + g * 4 + r;
        const int col = h * 64 + dt * 16 + l15;
        out[((long)(b * SEQ + q)) * D_MODEL + col] = f2b(o[mi][dt][r] * inv[mi][r]);
      }
}

// ---------------------------------------------------------------------------
// Residual + LN with fused 2-way split-K reduce
// ---------------------------------------------------------------------------
template<bool RES_F32, bool OUT_F32>
__global__ __launch_bounds__(256, 4)
void ln_ff2(const short* __restrict__ p0, const short* __restrict__ p1,
            const float* __restrict__ bias, const void* __restrict__ resv,
            const float* __restrict__ g, const float* __restrict__ beta,
            void* __restrict__ outv)
{
  __shared__ float red[8];
  const int row = blockIdx.x;
  const int tid = threadIdx.x;
  const int lane = tid & 63, w = tid >> 6;

  s16x4 v0 = *(const s16x4*)(p0 + (long)row * D_MODEL + tid * 4);
  s16x4 v1 = *(const s16x4*)(p1 + (long)row * D_MODEL + tid * 4);
  f32x4 vb = *(const f32x4*)(bias + tid * 4);
  float x[4];
  if (RES_F32) {
    f32x4 vr = *(const f32x4*)((const float*)resv + (long)row * D_MODEL + tid * 4);
    #pragma unroll
    for (int i = 0; i < 4; ++i) x[i] = vr[i] + b2f(v0[i]) + b2f(v1[i]) + vb[i];
  } else {
    s16x4 vr = *(const s16x4*)((const short*)resv + (long)row * D_MODEL + tid * 4);
    #pragma unroll
    for (int i = 0; i < 4; ++i) x[i] = b2f(vr[i]) + b2f(v0[i]) + b2f(v1[i]) + vb[i];
  }

  float sum = x[0] + x[1] + x[2] + x[3];
  #pragma unroll
  for (int msk = 32; msk >= 1; msk >>= 1) sum += __shfl_xor(sum, msk, 64);
  if (lane == 0) red[w] = sum;
  __syncthreads();
  sum = red[0] + red[1] + red[2] + red[3];
  const float mu = sum * (1.f / D_MODEL);

  float sq = 0.f;
  #pragma unroll
  for (int i = 0; i < 4; ++i) { float d = x[i] - mu; sq += d * d; }
  #pragma unroll
  for (int msk = 32; msk >= 1; msk >>= 1) sq += __shfl_xor(sq, msk, 64);
  if (lane == 0) red[4 + w] = sq;
  __syncthreads();
  sq = red[4] + red[5] + red[6] + red[7];
  const float rs = rsqrtf(sq * (1.f / D_MODEL) + 1e-5f);

  if (OUT_F32) {
    f32x4 ov;
    #pragma unroll
    for (int i = 0; i < 4; ++i) {
      const int c = tid * 4 + i;
      ov[i] = (x[i] - mu) * rs * g[c] + beta[c];
    }
    *(f32x4*)((float*)outv + (long)row * D_MODEL + tid * 4) = ov;
  } else {
    s16x4 ov;
    #pragma unroll
    for (int i = 0; i < 4; ++i) {
      const int c = tid * 4 + i;
      ov[i] = f2b((x[i] - mu) * rs * g[c] + beta[c]);
    }
    *(s16x4*)((short*)outv + (long)row * D_MODEL + tid * 4) = ov;
  }
}

// ---------------------------------------------------------------------------
// Final LN with fused 4-way split-K reduce -> f32 out
// ---------------------------------------------------------------------------
__global__ __launch_bounds__(256, 4)
void ln_ff4(const short* __restrict__ p0, const short* __restrict__ p1,
            const short* __restrict__ p2, const short* __restrict__ p3,
            const float* __restrict__ bias, const short* __restrict__ xres,
            const float* __restrict__ g, const float* __restrict__ beta,
            float* __restrict__ outv)
{
  __shared__ float red[8];
  const int row = blockIdx.x;
  const int tid = threadIdx.x;
  const int lane = tid & 63, w = tid >> 6;

  s16x4 v0 = *(const s16x4*)(p0 + (long)row * D_MODEL + tid * 4);
  s16x4 v1 = *(const s16x4*)(p1 + (long)row * D_MODEL + tid * 4);
  s16x4 v2 = *(const s16x4*)(p2 + (long)row * D_MODEL + tid * 4);
  s16x4 v3 = *(const s16x4*)(p3 + (long)row * D_MODEL + tid * 4);
  s16x4 vx = *(const s16x4*)(xres + (long)row * D_MODEL + tid * 4);
  f32x4 vb = *(const f32x4*)(bias + tid * 4);
  float x[4];
  #pragma unroll
  for (int i = 0; i < 4; ++i)
    x[i] = b2f(vx[i]) + b2f(v0[i]) + b2f(v1[i]) + b2f(v2[i]) + b2f(v3[i]) + vb[i];

  float sum = x[0] + x[1] + x[2] + x[3];
  #pragma unroll
  for (int msk = 32; msk >= 1; msk >>= 1) sum += __shfl_xor(sum, msk, 64);
  if (lane == 0) red[w] = sum;
  __syncthreads();
  sum = red[0] + red[1] + red[2] + red[3];
  const float mu = sum * (1.f / D_MODEL);

  float sq = 0.f;
  #pragma unroll
  for (int i = 0; i < 4; ++i) { float d = x[i] - mu; sq += d * d; }
  #pragma unroll
  for (int msk = 32; msk >= 1; msk >>= 1) sq += __shfl_xor(sq, msk, 64);
  if (lane == 0) red[4 + w] = sq;
  __syncthreads();
  sq = red[4] + red[5] + red[6] + red[7];
  const float rs = rsqrtf(sq * (1.f / D_MODEL) + 1e-5f);

  f32x4 ov;
  #pragma unroll
  for (int i = 0; i < 4; ++i) {
    const int c = tid * 4 + i;
    ov[i] = (x[i] - mu) * rs * g[c] + beta[c];
  }
  *(f32x4*)(outv + (long)row * D_MODEL + tid * 4) = ov;
}

// ---------------------------------------------------------------------------
// Residual + LayerNorm (fallback path)
// ---------------------------------------------------------------------------
template<bool RES_F32, bool OUT_F32>
__global__ __launch_bounds__(256, 4)
void ln_res(const short* __restrict__ a, const void* __restrict__ resv,
            const float* __restrict__ g, const float* __restrict__ beta,
            void* __restrict__ outv)
{
  __shared__ float red[8];
  const int row = blockIdx.x;
  const int tid = threadIdx.x;
  const int lane = tid & 63, w = tid >> 6;

  s16x4 va = *(const s16x4*)(a + (long)row * D_MODEL + tid * 4);
  float x[4];
  if (RES_F32) {
    f32x4 vr = *(const f32x4*)((const float*)resv + (long)row * D_MODEL + tid * 4);
    #pragma unroll
    for (int i = 0; i < 4; ++i) x[i] = b2f(va[i]) + vr[i];
  } else {
    s16x4 vr = *(const s16x4*)((const short*)resv + (long)row * D_MODEL + tid * 4);
    #pragma unroll
    for (int i = 0; i < 4; ++i) x[i] = b2f(va[i]) + b2f(vr[i]);
  }
  float sum = x[0] + x[1] + x[2] + x[3];
  #pragma unroll
  for (int msk = 32; msk >= 1; msk >>= 1) sum += __shfl_xor(sum, msk, 64);
  if (lane == 0) red[w] = sum;
  __syncthreads();
  sum = red[0] + red[1] + red[2] + red[3];
  const float mu = sum * (1.f / D_MODEL);

  float sq = 0.f;
  #pragma unroll
  for (int i = 0; i < 4; ++i) { float d = x[i] - mu; sq += d * d; }
  #pragma unroll
  for (int msk = 32; msk >= 1; msk >>= 1) sq += __shfl_xor(sq, msk, 64);
  if (lane == 0) red[4 + w] = sq;
  __syncthreads();
  sq = red[4] + red[5] + red[6] + red[7];
  const float rs = rsqrtf(sq * (1.f / D_MODEL) + 1e-5f);

  if (OUT_F32) {
    f32x4 ov;
    #pragma unroll
    for (int i = 0; i < 4; ++i) {
      const int c = tid * 4 + i;
      ov[i] = (x[i] - mu) * rs * g[c] + beta[c];
    }
    *(f32x4*)((float*)outv + (long)row * D_MODEL + tid * 4) = ov;
  } else {
    s16x4 ov;
    #pragma unroll
    for (int i = 0; i < 4; ++i) {
      const int c = tid * 4 + i;
      ov[i] = f2b((x[i] - mu) * rs * g[c] + beta[c]);
    }
    *(s16x4*)((short*)outv + (long)row * D_MODEL + tid * 4) = ov;
  }
}

// ---------------------------------------------------------------------------
// Merged f32->bf16 conversions + cached-V transpose
// ---------------------------------------------------------------------------
__global__ void cvt_all(const float* __restrict__ ck, const float* __restrict__ cv,
                        const float* __restrict__ src,
                        const float* __restrict__ Wq, const float* __restrict__ Wk,
                        const float* __restrict__ Wv, const float* __restrict__ Wo,
                        const float* __restrict__ W1, const float* __restrict__ W2,
                        short* __restrict__ k_ws, short* __restrict__ v_ws,
                        short* __restrict__ srcb,
                        short* __restrict__ Wqb, short* __restrict__ W1b,
                        short* __restrict__ W2b)
{
  for (int i = blockIdx.x * blockDim.x + threadIdx.x; i < 5767168;
       i += gridDim.x * blockDim.x) {
    if (i >= 5242880) {               // cached V -> V^T, 8-elem chunks
      const int j = i - 5242880;
      const int bh = j >> 14;
      const int rem = j & 16383;
      const int d = rem & 63;
      const int s0 = (rem >> 6) << 3;
      s16x8 r;
      #pragma unroll
      for (int k = 0; k < 8; ++k)
        r[k] = f2b(cv[((long)bh * SEQ + s0 + k) * 64 + d]);
      *(s16x8*)(v_ws + ((long)bh * 64 + d) * SEQ + s0) = r;
      continue;
    }
    const float* s; short* d; int li;
    if      (i < 1048576) { s = ck;  d = k_ws;           li = i; }
    else if (i < 2097152) { s = src; d = srcb;           li = i - 1048576; }
    else if (i < 2359296) { s = Wq;  d = Wqb;            li = i - 2097152; }
    else if (i < 2621440) { s = Wk;  d = Wqb + 1048576;  li = i - 2359296; }
    else if (i < 2883584) { s = Wv;  d = Wqb + 2097152;  li = i - 2621440; }
    else if (i < 3145728) { s = Wo;  d = Wqb + 3145728;  li = i - 2883584; }
    else if (i < 4194304) { s = W1;  d = W1b;            li = i - 3145728; }
    else                  { s = W2;  d = W2b;            li = i - 4194304; }
    f32x4 v = *(const f32x4*)(s + (long)li * 4);
    s16x4 r;
    #pragma unroll
    for (int j = 0; j < 4; ++j) r[j] = f2b(v[j]);
    *(s16x4*)(d + (long)li * 4) = r;
  }
}

// cached V (B,H,S,64) f32 -> V^T (B,H,64,S) bf16  (fallback path)
__global__ void cvt_v_t(const float* __restrict__ in, short* __restrict__ out)
{
  const int c2 = blockIdx.x * blockDim.x + threadIdx.x;
  const int bh = c2 >> 14;
  const int rem = c2 & 16383;
  const int d = rem & 63;
  const int s0 = (rem >> 6) << 3;
  s16x8 r;
  #pragma unroll
  for (int j = 0; j < 8; ++j)
    r[j] = f2b(in[((long)bh * SEQ + s0 + j) * 64 + d]);
  *(s16x8*)(out + ((long)bh * 64 + d) * SEQ + s0) = r;
}

// f32 -> bf16 (fallback path)
__global__ void cvt_f32_bf16(const f32x4* __restrict__ in, s16x4* __restrict__ out, int n4)
{
  for (int i = blockIdx.x * blockDim.x + threadIdx.x; i < n4; i += gridDim.x * blockDim.x) {
    f32x4 v = in[i];
    s16x4 r;
    #pragma unroll
    for (int j = 0; j < 4; ++j) r[j] = f2b(v[j]);
    out[i] = r;
  }
}

extern "C" void kernel_launch(void* const* d_in, const int* in_sizes, int n_in,
                              void* d_out, int out_size, void* d_ws, size_t ws_size,
                              hipStream_t stream)
{
  const float* src = (const float*)d_in[0];
  const int*   idx = (const int*)  d_in[1];
  const float* ck  = (const float*)d_in[2];
  const float* cv  = (const float*)d_in[3];
  const float* Wq  = (const float*)d_in[4];
  const float* bq  = (const float*)d_in[5];
  const float* Wk  = (const float*)d_in[6];
  const float* bk  = (const float*)d_in[7];
  const float* Wv  = (const float*)d_in[8];
  const float* bv  = (const float*)d_in[9];
  const float* Wo  = (const float*)d_in[10];
  const float* bo  = (const float*)d_in[11];
  const float* W1  = (const float*)d_in[12];
  const float* b1  = (const float*)d_in[13];
  const float* W2  = (const float*)d_in[14];
  const float* b2  = (const float*)d_in[15];
  const float* g1  = (const float*)d_in[16];
  const float* be1 = (const float*)d_in[17];
  const float* g2  = (const float*)d_in[18];
  const float* be2 = (const float*)d_in[19];
  float* out = (float*)d_out;

  char* ws = (char*)d_ws;
  const size_t SZ = (size_t)4096 * 1024 * 2;  // 8 MB = 1<<22 shorts
  short* x_ws    = (short*)(ws);              // region 0
  short* proj_ws = (short*)(ws + SZ);         // region 1: Wo p0 / FFN2 p0
  short* q_ws    = (short*)(ws + 2 * SZ);     // region 2: Q / Wo p1
  short* k_ws    = (short*)(ws + 3 * SZ);
  short* v_ws    = (short*)(ws + 4 * SZ);
  short* attn_ws = (short*)(ws + 5 * SZ);
  short* h_ws    = (short*)(ws + 2 * SZ);     // 32MB (2..5), after attn phase
  short* W1b     = (short*)(ws + 6 * SZ);     // FFN2 p1 (after FFN1)
  short* W2b     = (short*)(ws + 7 * SZ);
  short* srcb    = (short*)(ws + 8 * SZ);     // FFN2 p2
  short* Wqb     = (short*)(ws + 9 * SZ);     // proj weights; FFN2 p3
  const bool big = ws_size >= 10 * SZ;        // 80 MB

  const int M = BATCH * SEQ;      // 4096
  const int R = 409;
  const int Mr = BATCH * R;       // 818
  const int nkv4 = BATCH * NHEAD * SEQ * HEAD_DIM / 4;

  if (big) {
    cvt_all<<<2048, 256, 0, stream>>>(ck, cv, src, Wq, Wk, Wv, Wo, W1, W2,
                                      k_ws, v_ws, srcb, Wqb, W1b, W2b);
    // merged Q/K/V projections, BN=64 -> 736 blocks (~3/CU)
    gemm_nt<8, 64, false, false><<<dim3(16, 46), 256, 0, stream>>>(
        srcb, Wqb, bq, q_ws, M, 1024, 1024, idx, R, bk, bv, nullptr, nullptr, nullptr);
    attn_fwd<<<dim3(BATCH * NHEAD, SEQ / 128), 256, 0, stream>>>(q_ws, k_ws, v_ws, attn_ws);
    // Wo projection, split-K=2, BN=64 -> 1024 blocks (4/CU)
    gemm_nt<6, 64, false, false><<<dim3(16, 32, 2), 256, 0, stream>>>(
        attn_ws, Wqb + 3145728, nullptr, proj_ws, M, 1024, 1024, nullptr, 0,
        nullptr, nullptr, q_ws, nullptr, nullptr);
    ln_ff2<true, false><<<4096, 256, 0, stream>>>(proj_ws, q_ws, bo, src, g1, be1, x_ws);
    // FFN1: 256x256 32x32-MFMA pipeline, grid 16x16 = 256 blocks (1/CU)
    gemm_ff8<0><<<dim3(16, 16), 512, 0, stream>>>(
        x_ws, W1b, b1, h_ws, DFF, 1024, nullptr, nullptr, nullptr);
    // FFN2: split-K=4 -> partials proj_ws / W1b / srcb / Wqb
    gemm_ff8<1><<<dim3(4, 16, 4), 512, 0, stream>>>(
        h_ws, W2b, nullptr, proj_ws, 1024, 4096, W1b, srcb, Wqb);
    ln_ff4<<<4096, 256, 0, stream>>>(proj_ws, W1b, srcb, Wqb, b2, x_ws, g2, be2, out);
  } else {
    cvt_f32_bf16<<<2048, 256, 0, stream>>>((const f32x4*)ck, (s16x4*)k_ws, nkv4);
    cvt_v_t<<<2048, 256, 0, stream>>>(cv, v_ws);
    gemm_nt<2, 128, true, true><<<dim3(8, 32), 256, 0, stream>>>(
        src, Wq, bq, q_ws, M, 1024, 1024, nullptr, 0, nullptr, nullptr, nullptr, nullptr, nullptr);
    gemm_nt<3, 128, true, true><<<dim3(8, 7), 256, 0, stream>>>(
        src, Wk, bk, k_ws, Mr, 1024, 1024, idx, R, nullptr, nullptr, nullptr, nullptr, nullptr);
    gemm_nt<4, 128, true, true><<<dim3(8, 7), 256, 0, stream>>>(
        src, Wv, bv, v_ws, Mr, 1024, 1024, idx, R, nullptr, nullptr, nullptr, nullptr, nullptr);
    attn_fwd<<<dim3(BATCH * NHEAD, SEQ / 128), 256, 0, stream>>>(q_ws, k_ws, v_ws, attn_ws);
    gemm_nt<0, 128, false, true><<<dim3(8, 32), 256, 0, stream>>>(
        attn_ws, Wo, bo, proj_ws, M, 1024, 1024, nullptr, 0, nullptr, nullptr, nullptr, nullptr, nullptr);
    ln_res<true, false><<<4096, 256, 0, stream>>>(proj_ws, src, g1, be1, x_ws);
    gemm_nt<1, 128, false, true><<<dim3(32, 32), 256, 0, stream>>>(
        x_ws, W1, b1, h_ws, M, DFF, 1024, nullptr, 0, nullptr, nullptr, nullptr, nullptr, nullptr);
    gemm_nt<0, 128, false, true><<<dim3(8, 32), 256, 0, stream>>>(
        h_ws, W2, b2, proj_ws, M, 1024, DFF, nullptr, 0, nullptr, nullptr, nullptr, nullptr, nullptr);
    ln_res<false, true><<<4096, 256, 0, stream>>>(proj_ws, x_ws, g2, be2, out);
  }
}

// Round 17
// 224.253 us; speedup vs baseline: 1.0407x; 1.0407x over previous
//
#include <hip/hip_runtime.h>
#include <hip/hip_bf16.h>

typedef __attribute__((ext_vector_type(4))) float f32x4;
typedef __attribute__((ext_vector_type(16))) float f32x16;
typedef __attribute__((ext_vector_type(8))) short s16x8;
typedef __attribute__((ext_vector_type(4))) short s16x4;
typedef __attribute__((ext_vector_type(2))) short s16x2;

typedef __attribute__((address_space(1))) const unsigned int guint;
typedef __attribute__((address_space(3))) unsigned int luint;

#define D_MODEL 1024
#define NHEAD 16
#define HEAD_DIM 64
#define DFF 4096
#define SEQ 2048
#define BATCH 2
#define QSCALE 0.18033688011112042f   // 0.125 * log2(e); attn uses exp2

__device__ __forceinline__ float b2f(short s) {
  union { unsigned int u; float f; } v;
  v.u = ((unsigned int)(unsigned short)s) << 16;
  return v.f;
}
__device__ __forceinline__ short f2b(float f) {
  __hip_bfloat16 h = __float2bfloat16(f);
  return *reinterpret_cast<short*>(&h);
}
__device__ __forceinline__ s16x8 cvt8(f32x4 a, f32x4 b) {
  s16x8 r;
  #pragma unroll
  for (int i = 0; i < 4; ++i) { r[i] = f2b(a[i]); r[i + 4] = f2b(b[i]); }
  return r;
}

// ---------------------------------------------------------------------------
// FFN GEMM v4: 256x256 tile, BK=64, 512 thr = 8 waves (2m x 4n), per-wave
// 128x64 via 32x32x16 MFMA. KEY CHANGE (r17): frag-complete kk-halves —
// each LDS frag read EXACTLY ONCE per K-tile (24 ds_read_b128/wave/tile vs
// 48). LDS-pipe model: 384->192 reads/CU/tile; this was the binding pipe
// (MfmaUtil 27% == 2066/7350 cyc predicted by the read budget).
// kk-outer MFMA order spaces same-acc dependencies by 8 independent ops.
// LDS 128KB double-buffered, counted vmcnt(2), 2 barriers/tile, 3-bit slot
// swizzle both sides.
// MODE 0: relu(A@W^T+bias) (FFN1). MODE 1: split-K=4, bf16 partials (FFN2).
// ---------------------------------------------------------------------------
template<int MODE>
__global__ __launch_bounds__(512, 2)
void gemm_ff8(const short* __restrict__ A, const short* __restrict__ W,
              const float* __restrict__ bias, short* __restrict__ out,
              int N, int K,
              short* __restrict__ pB, short* __restrict__ pC,
              short* __restrict__ pD)
{
  __shared__ short Al[2][16384];   // 64 KB: [buf][slot(4)*4096 + lin]
  __shared__ short Bl[2][16384];   // 64 KB

  const int tid  = threadIdx.x;
  const int lane = tid & 63, wave = tid >> 6;
  const int l31 = lane & 31, hi = lane >> 5;
  const int wm = (wave >> 2) * 128;      // 0 / 128
  const int wn = (wave & 3) * 64;        // 0..192

  const int nwg = gridDim.x * gridDim.y;
  int lid = blockIdx.y * gridDim.x + blockIdx.x;
  if ((nwg & 7) == 0) lid = (lid & 7) * (nwg >> 3) + (lid >> 3);
  const int bn = lid % gridDim.x, bm = lid / gridDim.x;

  const int Keff = (MODE == 1) ? (K >> 2) : K;
  const int kOff = (MODE == 1) ? (int)blockIdx.z * Keff : 0;

  // staging: thread t covers tile row (slot*64 + t>>3); global col slot
  // pre-swizzled by row&7 = (t>>3)&7 (same 128B line -> coalesced)
  const int srow = tid >> 3;
  const int scol = (((tid & 7) ^ ((tid >> 3) & 7)) * 8);
  const short* gA = A + ((long)(bm * 256) + srow) * K + kOff + scol;
  const short* gW = W + ((long)(bn * 256) + srow) * K + kOff + scol;
  const long slotG = 64L * K;

  auto stage = [&](int buf, int slot, int k0) {
    luint* dA = (luint*)((short*)Al + buf * 16384 + slot * 4096 + wave * 512);
    luint* dB = (luint*)((short*)Bl + buf * 16384 + slot * 4096 + wave * 512);
    __builtin_amdgcn_global_load_lds((guint*)(gA + slot * slotG + k0), dA, 16, 0, 0);
    __builtin_amdgcn_global_load_lds((guint*)(gW + slot * slotG + k0), dB, 16, 0, 0);
  };

  const int sw = l31 & 7;   // row&7 for all frag reads (rows = base + l31)

  f32x16 acc[4][2] = {};

  // prologue: full tile 0 into buf 0 (8 glds per wave)
  #pragma unroll
  for (int s = 0; s < 4; ++s) stage(0, s, 0);

  const int nt = Keff / 64;
  int cur = 0;
  for (int t = 0; t < nt; ++t) {
    const int k1 = (t + 1) * 64;
    if (t + 1 < nt) {
      stage(cur ^ 1, 0, k1);                       // slot 0 early
      asm volatile("s_waitcnt vmcnt(2)" ::: "memory");   // tile t's 8 landed
    } else {
      asm volatile("s_waitcnt vmcnt(0)" ::: "memory");
    }
    __builtin_amdgcn_s_barrier();
    __builtin_amdgcn_sched_barrier(0);

    const short* Abuf = (const short*)Al + cur * 16384;
    const short* Bbuf = (const short*)Bl + cur * 16384;

    #pragma unroll
    for (int half = 0; half < 2; ++half) {
      // load ALL frags for this kk-half exactly once:
      // A: 4 mf x 2 kk (8 reads), B: 2 nf x 2 kk (4 reads)
      s16x8 av[4][2], bv2[2][2];
      #pragma unroll
      for (int mf = 0; mf < 4; ++mf) {
        const int row = wm + mf * 32 + l31;
        #pragma unroll
        for (int k2 = 0; k2 < 2; ++k2) {
          const int kk = half * 2 + k2;
          av[mf][k2] = *(const s16x8*)(Abuf + row * 64 + (((kk * 2 + hi) ^ sw) << 3));
        }
      }
      #pragma unroll
      for (int nf = 0; nf < 2; ++nf) {
        const int row = wn + nf * 32 + l31;
        #pragma unroll
        for (int k2 = 0; k2 < 2; ++k2) {
          const int kk = half * 2 + k2;
          bv2[nf][k2] = *(const s16x8*)(Bbuf + row * 64 + (((kk * 2 + hi) ^ sw) << 3));
        }
      }
      if (t + 1 < nt) {
        stage(cur ^ 1, half * 2 + 1, k1);
        if (half == 1) stage(cur ^ 1, 2, k1);   // slots 1,3 at halves; slot 2 here
      }

      __builtin_amdgcn_s_setprio(1);
      #pragma unroll
      for (int k2 = 0; k2 < 2; ++k2)            // kk outer: 8 indep ops between
        #pragma unroll
        for (int mf = 0; mf < 4; ++mf)          //   same-acc dependencies
          #pragma unroll
          for (int nf = 0; nf < 2; ++nf)
            acc[mf][nf] = __builtin_amdgcn_mfma_f32_32x32x16_bf16(
                av[mf][k2], bv2[nf][k2], acc[mf][nf], 0, 0, 0);
      __builtin_amdgcn_s_setprio(0);
    }

    __builtin_amdgcn_sched_barrier(0);
    __builtin_amdgcn_s_barrier();   // all reads of buf[cur] done
    cur ^= 1;
  }

  short* oz = out;
  if (MODE == 1) {
    const int z = blockIdx.z;
    oz = (z == 0) ? out : (z == 1) ? pB : (z == 2) ? pC : pD;
  }
  #pragma unroll
  for (int mf = 0; mf < 4; ++mf) {
    #pragma unroll
    for (int nf = 0; nf < 2; ++nf) {
      const int gn = bn * 256 + wn + nf * 32 + l31;
      const float bvv = (MODE == 0) ? bias[gn] : 0.f;
      #pragma unroll
      for (int reg = 0; reg < 16; ++reg) {
        const int gm = bm * 256 + wm + mf * 32 + (reg & 3) + 8 * (reg >> 2) + 4 * hi;
        float v = acc[mf][nf][reg] + bvv;
        if (MODE == 0) v = v > 0.f ? v : 0.f;
        oz[(long)gm * N + gn] = f2b(v);
      }
    }
  }
}

// ---------------------------------------------------------------------------
// NT GEMM (unchanged round-12): 256 thr = 4 waves, tile 128xBN, BK=32,
// counted-vmcnt raw-barrier double-buffer, slot-XOR swizzle, XCD swizzle.
// MODE 0/1; 2/3/4 fallback; 6 split-K; 8 merged QKV.
// ---------------------------------------------------------------------------
template<int MODE, int BN, bool AF32, bool WF32>
__global__ __launch_bounds__(256, 3)
void gemm_nt(const void* __restrict__ Av, const void* __restrict__ Wv,
             const float* __restrict__ bias, short* __restrict__ out,
             int M, int N, int K,
             const int* __restrict__ idx, int R,
             const float* __restrict__ bias2, const float* __restrict__ bias3,
             short* __restrict__ pB, short* __restrict__ pC,
             short* __restrict__ pD)
{
  constexpr bool GLDS = (!AF32 && !WF32);
  constexpr int NI = BN / 32;

  const float* Af = (const float*)Av;
  const short* Ab = (const short*)Av;
  const float* Wf = (const float*)Wv;
  const short* Wb = (const short*)Wv;

  const int tid  = threadIdx.x;
  const int lane = tid & 63, wave = tid >> 6;
  const int g = lane >> 4, l15 = lane & 15;
  const int wm = (wave & 1) * 64, wn = (wave >> 1) * (BN / 2);

  const int nwg = gridDim.x * gridDim.y;
  int lid = blockIdx.y * gridDim.x + blockIdx.x;
  if ((nwg & 7) == 0) lid = (lid & 7) * (nwg >> 3) + (lid >> 3);
  const int bn = lid % gridDim.x;
  const int bm0 = lid / gridDim.x;

  int task = 0, bm = bm0, Mt = M;
  if (MODE == 8) {
    if (bm0 < 32)      { task = 0; bm = bm0;      Mt = M; }
    else if (bm0 < 39) { task = 1; bm = bm0 - 32; Mt = BATCH * R; }
    else               { task = 2; bm = bm0 - 39; Mt = BATCH * R; }
  }

  f32x4 acc[4][NI] = {};

  if constexpr (GLDS) {
    __shared__ short As[2][128][32];
    __shared__ short Bs[2][BN][32];

    const short* Wbase = Wb + ((MODE == 8) ? ((size_t)task << 20) : 0);
    const int nz   = (MODE == 6) ? gridDim.z : 1;
    const int Keff = K / nz;
    const int kOff = (MODE == 6) ? (int)blockIdx.z * Keff : 0;

    const int rA0 = wave * 16 + (lane >> 2);
    const int rA1 = rA0 + 64;
    const int cs = (((lane & 3) ^ ((lane >> 3) & 3)) * 8);

    auto arow = [&](int r) -> long {
      const int gm = bm * 128 + r;
      const int am = gm < Mt ? gm : Mt - 1;
      if (MODE == 8 && task > 0) {
        const int b0 = am / R;
        return (long)(b0 * SEQ + idx[am - b0 * R]);
      }
      return am;
    };
    const long aR0 = arow(rA0), aR1 = arow(rA1);
    const long wR0 = (long)bn * BN + rA0;

    const short* gA0 = Ab + aR0 * K + kOff + cs;
    const short* gA1 = Ab + aR1 * K + kOff + cs;
    const short* gB0 = Wbase + wR0 * K + kOff + cs;
    const short* gB1 = nullptr;
    if constexpr (BN == 128) gB1 = Wbase + ((long)bn * BN + rA1) * K + kOff + cs;

    auto stage = [&](int buf, int k0) {
      luint* lA0 = (luint*)((short*)As + buf * 4096 + wave * 512);
      luint* lA1 = (luint*)((short*)As + buf * 4096 + (4 + wave) * 512);
      luint* lB0 = (luint*)((short*)Bs + buf * (BN * 32) + wave * 512);
      __builtin_amdgcn_global_load_lds((guint*)(gA0 + k0), lA0, 16, 0, 0);
      __builtin_amdgcn_global_load_lds((guint*)(gA1 + k0), lA1, 16, 0, 0);
      __builtin_amdgcn_global_load_lds((guint*)(gB0 + k0), lB0, 16, 0, 0);
      if constexpr (BN == 128) {
        luint* lB1 = (luint*)((short*)Bs + buf * (BN * 32) + (4 + wave) * 512);
        __builtin_amdgcn_global_load_lds((guint*)(gB1 + k0), lB1, 16, 0, 0);
      }
    };

    const int rcol = ((g ^ ((l15 >> 1) & 3)) * 8);

    const int nt = Keff / 32;
    stage(0, 0);
    int cur = 0;
    for (int t = 0; t < nt; ++t) {
      if (t + 1 < nt) {
        stage(cur ^ 1, (t + 1) * 32);
        if constexpr (BN == 128) asm volatile("s_waitcnt vmcnt(4)" ::: "memory");
        else                     asm volatile("s_waitcnt vmcnt(3)" ::: "memory");
      } else {
        asm volatile("s_waitcnt vmcnt(0)" ::: "memory");
      }
      __builtin_amdgcn_s_barrier();
      __builtin_amdgcn_sched_barrier(0);

      s16x8 af[4], bf4[NI];
      #pragma unroll
      for (int mi = 0; mi < 4; ++mi)
        af[mi] = *(const s16x8*)&As[cur][wm + mi * 16 + l15][rcol];
      #pragma unroll
      for (int ni = 0; ni < NI; ++ni)
        bf4[ni] = *(const s16x8*)&Bs[cur][wn + ni * 16 + l15][rcol];
      #pragma unroll
      for (int mi = 0; mi < 4; ++mi)
        #pragma unroll
        for (int ni = 0; ni < NI; ++ni)
          acc[mi][ni] = __builtin_amdgcn_mfma_f32_16x16x32_bf16(af[mi], bf4[ni], acc[mi][ni], 0, 0, 0);

      __builtin_amdgcn_sched_barrier(0);
      __builtin_amdgcn_s_barrier();
      cur ^= 1;
    }
  } else {
    __shared__ short As[128][40];
    __shared__ short Bs[128][40];
    const int r0 = tid >> 1, c0 = (tid & 1) * 16;
    const int gm0 = bm * 128 + r0;
    const int am0 = gm0 < M ? gm0 : M - 1;
    long aRow0;
    if (MODE == 3 || MODE == 4) {
      const int b0 = am0 / R;
      aRow0 = (long)(b0 * SEQ + idx[am0 - b0 * R]);
    } else {
      aRow0 = am0;
    }
    const long wRow0 = bn * 128 + r0;

    for (int k0 = 0; k0 < K; k0 += 32) {
      __syncthreads();
      if (AF32) {
        f32x4 a0 = *(const f32x4*)(Af + aRow0 * K + k0 + c0);
        f32x4 a1 = *(const f32x4*)(Af + aRow0 * K + k0 + c0 + 4);
        f32x4 a2 = *(const f32x4*)(Af + aRow0 * K + k0 + c0 + 8);
        f32x4 a3 = *(const f32x4*)(Af + aRow0 * K + k0 + c0 + 12);
        *(s16x8*)&As[r0][c0]     = cvt8(a0, a1);
        *(s16x8*)&As[r0][c0 + 8] = cvt8(a2, a3);
      } else {
        *(s16x8*)&As[r0][c0]     = *(const s16x8*)(Ab + aRow0 * K + k0 + c0);
        *(s16x8*)&As[r0][c0 + 8] = *(const s16x8*)(Ab + aRow0 * K + k0 + c0 + 8);
      }
      if (WF32) {
        f32x4 w0 = *(const f32x4*)(Wf + wRow0 * K + k0 + c0);
        f32x4 w1 = *(const f32x4*)(Wf + wRow0 * K + k0 + c0 + 4);
        f32x4 w2 = *(const f32x4*)(Wf + wRow0 * K + k0 + c0 + 8);
        f32x4 w3 = *(const f32x4*)(Wf + wRow0 * K + k0 + c0 + 12);
        *(s16x8*)&Bs[r0][c0]     = cvt8(w0, w1);
        *(s16x8*)&Bs[r0][c0 + 8] = cvt8(w2, w3);
      } else {
        *(s16x8*)&Bs[r0][c0]     = *(const s16x8*)(Wb + wRow0 * K + k0 + c0);
        *(s16x8*)&Bs[r0][c0 + 8] = *(const s16x8*)(Wb + wRow0 * K + k0 + c0 + 8);
      }
      __syncthreads();

      s16x8 af[4], bf4[4];
      #pragma unroll
      for (int mi = 0; mi < 4; ++mi)
        af[mi] = *(const s16x8*)&As[wm + mi * 16 + l15][g * 8];
      #pragma unroll
      for (int ni = 0; ni < 4; ++ni)
        bf4[ni] = *(const s16x8*)&Bs[wn + ni * 16 + l15][g * 8];
      #pragma unroll
      for (int mi = 0; mi < 4; ++mi)
        #pragma unroll
        for (int ni = 0; ni < 4; ++ni)
          acc[mi][ni % NI] = __builtin_amdgcn_mfma_f32_16x16x32_bf16(af[mi], bf4[ni], acc[mi][ni % NI], 0, 0, 0);
    }
  }

  short* outz = out;
  if (MODE == 6) {
    const int z = blockIdx.z;
    outz = (z == 0) ? out : (z == 1) ? pB : (z == 2) ? pC : pD;
  }

  #pragma unroll
  for (int mi = 0; mi < 4; ++mi) {
    #pragma unroll
    for (int ni = 0; ni < NI; ++ni) {
      const int gn = bn * BN + wn + ni * 16 + l15;
      float bv;
      if (MODE == 6)      bv = 0.f;
      else if (MODE == 8) bv = (task == 0) ? bias[gn] : (task == 1) ? bias2[gn] : bias3[gn];
      else                bv = bias[gn];
      #pragma unroll
      for (int r = 0; r < 4; ++r) {
        const int gm = bm * 128 + wm + mi * 16 + g * 4 + r;
        if (MODE == 8) { if (gm >= Mt) continue; }
        else           { if (gm >= M)  continue; }
        float v = acc[mi][ni][r] + bv;
        if (MODE == 1) v = v > 0.f ? v : 0.f;
        if (MODE == 2) v *= QSCALE;
        if (MODE == 0 || MODE == 1) {
          out[(long)gm * N + gn] = f2b(v);
        } else if (MODE == 2) {
          const int b = gm >> 11, s = gm & (SEQ - 1);
          const int h = gn >> 6, d = gn & 63;
          out[(((long)(b * NHEAD + h)) * SEQ + s) * 64 + d] = f2b(v);
        } else if (MODE == 3) {
          const int b = gm / R, s = idx[gm - b * R];
          const int h = gn >> 6, d = gn & 63;
          out[(((long)(b * NHEAD + h)) * SEQ + s) * 64 + d] = f2b(v);
        } else if (MODE == 4) {
          const int b = gm / R, s = idx[gm - b * R];
          const int h = gn >> 6, d = gn & 63;
          out[(((long)(b * NHEAD + h)) * 64 + d) * SEQ + s] = f2b(v);
        } else if (MODE == 6) {
          outz[(long)gm * N + gn] = f2b(v);
        } else {  // MODE 8
          const int h = gn >> 6, d = gn & 63;
          if (task == 0) {
            const int b = gm >> 11, s = gm & (SEQ - 1);
            out[(((long)(b * NHEAD + h)) * SEQ + s) * 64 + d] = f2b(v * QSCALE);
          } else if (task == 1) {
            const int b = gm / R, s = idx[gm - b * R];
            (out + (1L << 22))[(((long)(b * NHEAD + h)) * SEQ + s) * 64 + d] = f2b(v);
          } else {
            const int b = gm / R, s = idx[gm - b * R];
            (out + (1L << 23))[(((long)(b * NHEAD + h)) * 64 + d) * SEQ + s] = f2b(v);
          }
        }
      }
    }
  }
}

// ---------------------------------------------------------------------------
// Flash attention fwd v4 (unchanged): swapped QK^T, permlane P, pre-swizzled
// glds staging, exp2, ones-MFMA row-sum, counted-vmcnt raw-barrier loop.
// ---------------------------------------------------------------------------
__global__ __launch_bounds__(256, 2)
void attn_fwd(const short* __restrict__ Q, const short* __restrict__ Kf,
              const short* __restrict__ Vt, short* __restrict__ out)
{
  __shared__ short Kl[2][64][64];
  __shared__ short Vl[2][64][64];

  const int tid  = threadIdx.x;
  const int lane = tid & 63, w = tid >> 6;
  const int g = lane >> 4, l15 = lane & 15;
  const int bh = blockIdx.x;
  const int qt = blockIdx.y;
  const int b  = bh >> 4, h = bh & 15;

  const long base = (long)bh * SEQ * 64;
  const int  q0   = qt * 128 + w * 32;

  s16x8 qf[2][2];
  #pragma unroll
  for (int mi = 0; mi < 2; ++mi)
    #pragma unroll
    for (int c = 0; c < 2; ++c)
      qf[mi][c] = *(const s16x8*)(Q + base + (long)(q0 + mi * 16 + l15) * 64 + c * 32 + g * 8);

  f32x4 o[2][4] = {};
  f32x4 os[2] = {};

  s16x8 ones;
  #pragma unroll
  for (int j = 0; j < 8; ++j) ones[j] = (short)0x3F80;

  auto ldsw = [](short (*buf)[64], int row, int slot) -> short* {
    return (short*)((char*)&buf[0][0] + row * 128 + ((slot ^ (row & 7)) << 4));
  };

  const int bo0 = w * 2048 + lane * 16;
  const int bo1 = bo0 + 1024;
  const int row0 = bo0 >> 7, ss0 = (((bo0 >> 4) & 7) ^ (row0 & 7));
  const int row1 = bo1 >> 7, ss1 = (((bo1 >> 4) & 7) ^ (row1 & 7));
  const short* gK0 = Kf + base + row0 * 64 + ss0 * 8;
  const short* gK1 = Kf + base + row1 * 64 + ss1 * 8;
  const short* gV0 = Vt + base + (long)row0 * SEQ + ss0 * 8;
  const short* gV1 = Vt + base + (long)row1 * SEQ + ss1 * 8;

  auto stage = [&](int buf, int t) {
    char* kb8 = (char*)&Kl[buf][0][0] + w * 2048;
    char* vb8 = (char*)&Vl[buf][0][0] + w * 2048;
    __builtin_amdgcn_global_load_lds((guint*)(gK0 + t * 4096), (luint*)kb8, 16, 0, 0);
    __builtin_amdgcn_global_load_lds((guint*)(gK1 + t * 4096), (luint*)(kb8 + 1024), 16, 0, 0);
    __builtin_amdgcn_global_load_lds((guint*)(gV0 + t * 64), (luint*)vb8, 16, 0, 0);
    __builtin_amdgcn_global_load_lds((guint*)(gV1 + t * 64), (luint*)(vb8 + 1024), 16, 0, 0);
  };

  stage(0, 0);
  int cur = 0;
  for (int t = 0; t < SEQ / 64; ++t) {
    if (t + 1 < SEQ / 64) {
      stage(cur ^ 1, t + 1);
      asm volatile("s_waitcnt vmcnt(4)" ::: "memory");
    } else {
      asm volatile("s_waitcnt vmcnt(0)" ::: "memory");
    }
    __builtin_amdgcn_s_barrier();
    __builtin_amdgcn_sched_barrier(0);

    f32x4 sc[2][4] = {};
    __builtin_amdgcn_s_setprio(1);
    #pragma unroll
    for (int c = 0; c < 2; ++c)
      #pragma unroll
      for (int n = 0; n < 4; ++n) {
        s16x8 kb = *(const s16x8*)ldsw(Kl[cur], n * 16 + l15, c * 4 + g);
        sc[0][n] = __builtin_amdgcn_mfma_f32_16x16x32_bf16(kb, qf[0][c], sc[0][n], 0, 0, 0);
        sc[1][n] = __builtin_amdgcn_mfma_f32_16x16x32_bf16(kb, qf[1][c], sc[1][n], 0, 0, 0);
      }
    __builtin_amdgcn_s_setprio(0);

    s16x8 pa[2][2];
    #pragma unroll
    for (int mi = 0; mi < 2; ++mi) {
      #pragma unroll
      for (int n = 0; n < 4; ++n)
        #pragma unroll
        for (int r = 0; r < 4; ++r) {
          float e;
          asm("v_exp_f32 %0, %1" : "=v"(e) : "v"(sc[mi][n][r]));
          sc[mi][n][r] = e;
        }
      unsigned int wpk[4][2];
      #pragma unroll
      for (int n = 0; n < 4; ++n)
        #pragma unroll
        for (int p = 0; p < 2; ++p)
          asm("v_cvt_pk_bf16_f32 %0, %1, %2"
              : "=v"(wpk[n][p]) : "v"(sc[mi][n][2 * p]), "v"(sc[mi][n][2 * p + 1]));
      #pragma unroll
      for (int c = 0; c < 2; ++c) {
        union { s16x8 v; unsigned int u[4]; } pu;
        #pragma unroll
        for (int p = 0; p < 2; ++p) {
          unsigned int a = wpk[2 * c][p], bb = wpk[2 * c + 1][p];
          asm volatile("v_permlane32_swap_b32 %0, %1" : "+v"(a), "+v"(bb));
          asm volatile("v_permlane16_swap_b32 %0, %1" : "+v"(a), "+v"(bb));
          pu.u[p]     = a;
          pu.u[2 + p] = bb;
        }
        pa[mi][c] = pu.v;
      }
    }

    __builtin_amdgcn_s_setprio(1);
    #pragma unroll
    for (int dt = 0; dt < 4; ++dt)
      #pragma unroll
      for (int c = 0; c < 2; ++c) {
        s16x8 vb = *(const s16x8*)ldsw(Vl[cur], dt * 16 + l15, c * 4 + g);
        o[0][dt] = __builtin_amdgcn_mfma_f32_16x16x32_bf16(pa[0][c], vb, o[0][dt], 0, 0, 0);
        o[1][dt] = __builtin_amdgcn_mfma_f32_16x16x32_bf16(pa[1][c], vb, o[1][dt], 0, 0, 0);
      }
    #pragma unroll
    for (int mi = 0; mi < 2; ++mi)
      #pragma unroll
      for (int c = 0; c < 2; ++c)
        os[mi] = __builtin_amdgcn_mfma_f32_16x16x32_bf16(pa[mi][c], ones, os[mi], 0, 0, 0);
    __builtin_amdgcn_s_setprio(0);

    __builtin_amdgcn_sched_barrier(0);
    __builtin_amdgcn_s_barrier();
    cur ^= 1;
  }

  float inv[2][4];
  #pragma unroll
  for (int mi = 0; mi < 2; ++mi)
    #pragma unroll
    for (int r = 0; r < 4; ++r)
      inv[mi][r] = 1.0f / os[mi][r];

  #pragma unroll
  for (int mi = 0; mi < 2; ++mi)
    #pragma unroll
    for (int dt = 0; dt < 4; ++dt)
      #pragma unroll
      for (int r = 0; r < 4; ++r) {
        const int q   = q0 + mi * 16 + g * 4 + r;
        const int col = h * 64 + dt * 16 + l15;
        out[((long)(b * SEQ + q)) * D_MODEL + col] = f2b(o[mi][dt][r] * inv[mi][r]);
      }
}

// ---------------------------------------------------------------------------
// Residual + LN with fused 2-way split-K reduce
// ---------------------------------------------------------------------------
template<bool RES_F32, bool OUT_F32>
__global__ __launch_bounds__(256, 4)
void ln_ff2(const short* __restrict__ p0, const short* __restrict__ p1,
            const float* __restrict__ bias, const void* __restrict__ resv,
            const float* __restrict__ g, const float* __restrict__ beta,
            void* __restrict__ outv)
{
  __shared__ float red[8];
  const int row = blockIdx.x;
  const int tid = threadIdx.x;
  const int lane = tid & 63, w = tid >> 6;

  s16x4 v0 = *(const s16x4*)(p0 + (long)row * D_MODEL + tid * 4);
  s16x4 v1 = *(const s16x4*)(p1 + (long)row * D_MODEL + tid * 4);
  f32x4 vb = *(const f32x4*)(bias + tid * 4);
  float x[4];
  if (RES_F32) {
    f32x4 vr = *(const f32x4*)((const float*)resv + (long)row * D_MODEL + tid * 4);
    #pragma unroll
    for (int i = 0; i < 4; ++i) x[i] = vr[i] + b2f(v0[i]) + b2f(v1[i]) + vb[i];
  } else {
    s16x4 vr = *(const s16x4*)((const short*)resv + (long)row * D_MODEL + tid * 4);
    #pragma unroll
    for (int i = 0; i < 4; ++i) x[i] = b2f(vr[i]) + b2f(v0[i]) + b2f(v1[i]) + vb[i];
  }

  float sum = x[0] + x[1] + x[2] + x[3];
  #pragma unroll
  for (int msk = 32; msk >= 1; msk >>= 1) sum += __shfl_xor(sum, msk, 64);
  if (lane == 0) red[w] = sum;
  __syncthreads();
  sum = red[0] + red[1] + red[2] + red[3];
  const float mu = sum * (1.f / D_MODEL);

  float sq = 0.f;
  #pragma unroll
  for (int i = 0; i < 4; ++i) { float d = x[i] - mu; sq += d * d; }
  #pragma unroll
  for (int msk = 32; msk >= 1; msk >>= 1) sq += __shfl_xor(sq, msk, 64);
  if (lane == 0) red[4 + w] = sq;
  __syncthreads();
  sq = red[4] + red[5] + red[6] + red[7];
  const float rs = rsqrtf(sq * (1.f / D_MODEL) + 1e-5f);

  if (OUT_F32) {
    f32x4 ov;
    #pragma unroll
    for (int i = 0; i < 4; ++i) {
      const int c = tid * 4 + i;
      ov[i] = (x[i] - mu) * rs * g[c] + beta[c];
    }
    *(f32x4*)((float*)outv + (long)row * D_MODEL + tid * 4) = ov;
  } else {
    s16x4 ov;
    #pragma unroll
    for (int i = 0; i < 4; ++i) {
      const int c = tid * 4 + i;
      ov[i] = f2b((x[i] - mu) * rs * g[c] + beta[c]);
    }
    *(s16x4*)((short*)outv + (long)row * D_MODEL + tid * 4) = ov;
  }
}

// ---------------------------------------------------------------------------
// Final LN with fused 4-way split-K reduce -> f32 out
// ---------------------------------------------------------------------------
__global__ __launch_bounds__(256, 4)
void ln_ff4(const short* __restrict__ p0, const short* __restrict__ p1,
            const short* __restrict__ p2, const short* __restrict__ p3,
            const float* __restrict__ bias, const short* __restrict__ xres,
            const float* __restrict__ g, const float* __restrict__ beta,
            float* __restrict__ outv)
{
  __shared__ float red[8];
  const int row = blockIdx.x;
  const int tid = threadIdx.x;
  const int lane = tid & 63, w = tid >> 6;

  s16x4 v0 = *(const s16x4*)(p0 + (long)row * D_MODEL + tid * 4);
  s16x4 v1 = *(const s16x4*)(p1 + (long)row * D_MODEL + tid * 4);
  s16x4 v2 = *(const s16x4*)(p2 + (long)row * D_MODEL + tid * 4);
  s16x4 v3 = *(const s16x4*)(p3 + (long)row * D_MODEL + tid * 4);
  s16x4 vx = *(const s16x4*)(xres + (long)row * D_MODEL + tid * 4);
  f32x4 vb = *(const f32x4*)(bias + tid * 4);
  float x[4];
  #pragma unroll
  for (int i = 0; i < 4; ++i)
    x[i] = b2f(vx[i]) + b2f(v0[i]) + b2f(v1[i]) + b2f(v2[i]) + b2f(v3[i]) + vb[i];

  float sum = x[0] + x[1] + x[2] + x[3];
  #pragma unroll
  for (int msk = 32; msk >= 1; msk >>= 1) sum += __shfl_xor(sum, msk, 64);
  if (lane == 0) red[w] = sum;
  __syncthreads();
  sum = red[0] + red[1] + red[2] + red[3];
  const float mu = sum * (1.f / D_MODEL);

  float sq = 0.f;
  #pragma unroll
  for (int i = 0; i < 4; ++i) { float d = x[i] - mu; sq += d * d; }
  #pragma unroll
  for (int msk = 32; msk >= 1; msk >>= 1) sq += __shfl_xor(sq, msk, 64);
  if (lane == 0) red[4 + w] = sq;
  __syncthreads();
  sq = red[4] + red[5] + red[6] + red[7];
  const float rs = rsqrtf(sq * (1.f / D_MODEL) + 1e-5f);

  f32x4 ov;
  #pragma unroll
  for (int i = 0; i < 4; ++i) {
    const int c = tid * 4 + i;
    ov[i] = (x[i] - mu) * rs * g[c] + beta[c];
  }
  *(f32x4*)(outv + (long)row * D_MODEL + tid * 4) = ov;
}

// ---------------------------------------------------------------------------
// Residual + LayerNorm (fallback path)
// ---------------------------------------------------------------------------
template<bool RES_F32, bool OUT_F32>
__global__ __launch_bounds__(256, 4)
void ln_res(const short* __restrict__ a, const void* __restrict__ resv,
            const float* __restrict__ g, const float* __restrict__ beta,
            void* __restrict__ outv)
{
  __shared__ float red[8];
  const int row = blockIdx.x;
  const int tid = threadIdx.x;
  const int lane = tid & 63, w = tid >> 6;

  s16x4 va = *(const s16x4*)(a + (long)row * D_MODEL + tid * 4);
  float x[4];
  if (RES_F32) {
    f32x4 vr = *(const f32x4*)((const float*)resv + (long)row * D_MODEL + tid * 4);
    #pragma unroll
    for (int i = 0; i < 4; ++i) x[i] = b2f(va[i]) + vr[i];
  } else {
    s16x4 vr = *(const s16x4*)((const short*)resv + (long)row * D_MODEL + tid * 4);
    #pragma unroll
    for (int i = 0; i < 4; ++i) x[i] = b2f(va[i]) + b2f(vr[i]);
  }
  float sum = x[0] + x[1] + x[2] + x[3];
  #pragma unroll
  for (int msk = 32; msk >= 1; msk >>= 1) sum += __shfl_xor(sum, msk, 64);
  if (lane == 0) red[w] = sum;
  __syncthreads();
  sum = red[0] + red[1] + red[2] + red[3];
  const float mu = sum * (1.f / D_MODEL);

  float sq = 0.f;
  #pragma unroll
  for (int i = 0; i < 4; ++i) { float d = x[i] - mu; sq += d * d; }
  #pragma unroll
  for (int msk = 32; msk >= 1; msk >>= 1) sq += __shfl_xor(sq, msk, 64);
  if (lane == 0) red[4 + w] = sq;
  __syncthreads();
  sq = red[4] + red[5] + red[6] + red[7];
  const float rs = rsqrtf(sq * (1.f / D_MODEL) + 1e-5f);

  if (OUT_F32) {
    f32x4 ov;
    #pragma unroll
    for (int i = 0; i < 4; ++i) {
      const int c = tid * 4 + i;
      ov[i] = (x[i] - mu) * rs * g[c] + beta[c];
    }
    *(f32x4*)((float*)outv + (long)row * D_MODEL + tid * 4) = ov;
  } else {
    s16x4 ov;
    #pragma unroll
    for (int i = 0; i < 4; ++i) {
      const int c = tid * 4 + i;
      ov[i] = f2b((x[i] - mu) * rs * g[c] + beta[c]);
    }
    *(s16x4*)((short*)outv + (long)row * D_MODEL + tid * 4) = ov;
  }
}

// ---------------------------------------------------------------------------
// Merged f32->bf16 conversions + cached-V transpose
// ---------------------------------------------------------------------------
__global__ void cvt_all(const float* __restrict__ ck, const float* __restrict__ cv,
                        const float* __restrict__ src,
                        const float* __restrict__ Wq, const float* __restrict__ Wk,
                        const float* __restrict__ Wv, const float* __restrict__ Wo,
                        const float* __restrict__ W1, const float* __restrict__ W2,
                        short* __restrict__ k_ws, short* __restrict__ v_ws,
                        short* __restrict__ srcb,
                        short* __restrict__ Wqb, short* __restrict__ W1b,
                        short* __restrict__ W2b)
{
  for (int i = blockIdx.x * blockDim.x + threadIdx.x; i < 5767168;
       i += gridDim.x * blockDim.x) {
    if (i >= 5242880) {               // cached V -> V^T, 8-elem chunks
      const int j = i - 5242880;
      const int bh = j >> 14;
      const int rem = j & 16383;
      const int d = rem & 63;
      const int s0 = (rem >> 6) << 3;
      s16x8 r;
      #pragma unroll
      for (int k = 0; k < 8; ++k)
        r[k] = f2b(cv[((long)bh * SEQ + s0 + k) * 64 + d]);
      *(s16x8*)(v_ws + ((long)bh * 64 + d) * SEQ + s0) = r;
      continue;
    }
    const float* s; short* d; int li;
    if      (i < 1048576) { s = ck;  d = k_ws;           li = i; }
    else if (i < 2097152) { s = src; d = srcb;           li = i - 1048576; }
    else if (i < 2359296) { s = Wq;  d = Wqb;            li = i - 2097152; }
    else if (i < 2621440) { s = Wk;  d = Wqb + 1048576;  li = i - 2359296; }
    else if (i < 2883584) { s = Wv;  d = Wqb + 2097152;  li = i - 2621440; }
    else if (i < 3145728) { s = Wo;  d = Wqb + 3145728;  li = i - 2883584; }
    else if (i < 4194304) { s = W1;  d = W1b;            li = i - 3145728; }
    else                  { s = W2;  d = W2b;            li = i - 4194304; }
    f32x4 v = *(const f32x4*)(s + (long)li * 4);
    s16x4 r;
    #pragma unroll
    for (int j = 0; j < 4; ++j) r[j] = f2b(v[j]);
    *(s16x4*)(d + (long)li * 4) = r;
  }
}

// cached V (B,H,S,64) f32 -> V^T (B,H,64,S) bf16  (fallback path)
__global__ void cvt_v_t(const float* __restrict__ in, short* __restrict__ out)
{
  const int c2 = blockIdx.x * blockDim.x + threadIdx.x;
  const int bh = c2 >> 14;
  const int rem = c2 & 16383;
  const int d = rem & 63;
  const int s0 = (rem >> 6) << 3;
  s16x8 r;
  #pragma unroll
  for (int j = 0; j < 8; ++j)
    r[j] = f2b(in[((long)bh * SEQ + s0 + j) * 64 + d]);
  *(s16x8*)(out + ((long)bh * 64 + d) * SEQ + s0) = r;
}

// f32 -> bf16 (fallback path)
__global__ void cvt_f32_bf16(const f32x4* __restrict__ in, s16x4* __restrict__ out, int n4)
{
  for (int i = blockIdx.x * blockDim.x + threadIdx.x; i < n4; i += gridDim.x * blockDim.x) {
    f32x4 v = in[i];
    s16x4 r;
    #pragma unroll
    for (int j = 0; j < 4; ++j) r[j] = f2b(v[j]);
    out[i] = r;
  }
}

extern "C" void kernel_launch(void* const* d_in, const int* in_sizes, int n_in,
                              void* d_out, int out_size, void* d_ws, size_t ws_size,
                              hipStream_t stream)
{
  const float* src = (const float*)d_in[0];
  const int*   idx = (const int*)  d_in[1];
  const float* ck  = (const float*)d_in[2];
  const float* cv  = (const float*)d_in[3];
  const float* Wq  = (const float*)d_in[4];
  const float* bq  = (const float*)d_in[5];
  const float* Wk  = (const float*)d_in[6];
  const float* bk  = (const float*)d_in[7];
  const float* Wv  = (const float*)d_in[8];
  const float* bv  = (const float*)d_in[9];
  const float* Wo  = (const float*)d_in[10];
  const float* bo  = (const float*)d_in[11];
  const float* W1  = (const float*)d_in[12];
  const float* b1  = (const float*)d_in[13];
  const float* W2  = (const float*)d_in[14];
  const float* b2  = (const float*)d_in[15];
  const float* g1  = (const float*)d_in[16];
  const float* be1 = (const float*)d_in[17];
  const float* g2  = (const float*)d_in[18];
  const float* be2 = (const float*)d_in[19];
  float* out = (float*)d_out;

  char* ws = (char*)d_ws;
  const size_t SZ = (size_t)4096 * 1024 * 2;  // 8 MB = 1<<22 shorts
  short* x_ws    = (short*)(ws);              // region 0
  short* proj_ws = (short*)(ws + SZ);         // region 1: Wo p0 / FFN2 p0
  short* q_ws    = (short*)(ws + 2 * SZ);     // region 2: Q / Wo p1
  short* k_ws    = (short*)(ws + 3 * SZ);
  short* v_ws    = (short*)(ws + 4 * SZ);
  short* attn_ws = (short*)(ws + 5 * SZ);
  short* h_ws    = (short*)(ws + 2 * SZ);     // 32MB (2..5), after attn phase
  short* W1b     = (short*)(ws + 6 * SZ);     // FFN2 p1 (after FFN1)
  short* W2b     = (short*)(ws + 7 * SZ);
  short* srcb    = (short*)(ws + 8 * SZ);     // FFN2 p2
  short* Wqb     = (short*)(ws + 9 * SZ);     // proj weights; FFN2 p3
  const bool big = ws_size >= 10 * SZ;        // 80 MB

  const int M = BATCH * SEQ;      // 4096
  const int R = 409;
  const int Mr = BATCH * R;       // 818
  const int nkv4 = BATCH * NHEAD * SEQ * HEAD_DIM / 4;

  if (big) {
    cvt_all<<<2048, 256, 0, stream>>>(ck, cv, src, Wq, Wk, Wv, Wo, W1, W2,
                                      k_ws, v_ws, srcb, Wqb, W1b, W2b);
    // merged Q/K/V projections, BN=64 -> 736 blocks (~3/CU)
    gemm_nt<8, 64, false, false><<<dim3(16, 46), 256, 0, stream>>>(
        srcb, Wqb, bq, q_ws, M, 1024, 1024, idx, R, bk, bv, nullptr, nullptr, nullptr);
    attn_fwd<<<dim3(BATCH * NHEAD, SEQ / 128), 256, 0, stream>>>(q_ws, k_ws, v_ws, attn_ws);
    // Wo projection, split-K=2, BN=64 -> 1024 blocks (4/CU)
    gemm_nt<6, 64, false, false><<<dim3(16, 32, 2), 256, 0, stream>>>(
        attn_ws, Wqb + 3145728, nullptr, proj_ws, M, 1024, 1024, nullptr, 0,
        nullptr, nullptr, q_ws, nullptr, nullptr);
    ln_ff2<true, false><<<4096, 256, 0, stream>>>(proj_ws, q_ws, bo, src, g1, be1, x_ws);
    // FFN1: 256x256, frag-complete kk-halves, grid 16x16 = 256 blocks
    gemm_ff8<0><<<dim3(16, 16), 512, 0, stream>>>(
        x_ws, W1b, b1, h_ws, DFF, 1024, nullptr, nullptr, nullptr);
    // FFN2: split-K=4 -> partials proj_ws / W1b / srcb / Wqb
    gemm_ff8<1><<<dim3(4, 16, 4), 512, 0, stream>>>(
        h_ws, W2b, nullptr, proj_ws, 1024, 4096, W1b, srcb, Wqb);
    ln_ff4<<<4096, 256, 0, stream>>>(proj_ws, W1b, srcb, Wqb, b2, x_ws, g2, be2, out);
  } else {
    cvt_f32_bf16<<<2048, 256, 0, stream>>>((const f32x4*)ck, (s16x4*)k_ws, nkv4);
    cvt_v_t<<<2048, 256, 0, stream>>>(cv, v_ws);
    gemm_nt<2, 128, true, true><<<dim3(8, 32), 256, 0, stream>>>(
        src, Wq, bq, q_ws, M, 1024, 1024, nullptr, 0, nullptr, nullptr, nullptr, nullptr, nullptr);
    gemm_nt<3, 128, true, true><<<dim3(8, 7), 256, 0, stream>>>(
        src, Wk, bk, k_ws, Mr, 1024, 1024, idx, R, nullptr, nullptr, nullptr, nullptr, nullptr);
    gemm_nt<4, 128, true, true><<<dim3(8, 7), 256, 0, stream>>>(
        src, Wv, bv, v_ws, Mr, 1024, 1024, idx, R, nullptr, nullptr, nullptr, nullptr, nullptr);
    attn_fwd<<<dim3(BATCH * NHEAD, SEQ / 128), 256, 0, stream>>>(q_ws, k_ws, v_ws, attn_ws);
    gemm_nt<0, 128, false, true><<<dim3(8, 32), 256, 0, stream>>>(
        attn_ws, Wo, bo, proj_ws, M, 1024, 1024, nullptr, 0, nullptr, nullptr, nullptr, nullptr, nullptr);
    ln_res<true, false><<<4096, 256, 0, stream>>>(proj_ws, src, g1, be1, x_ws);
    gemm_nt<1, 128, false, true><<<dim3(32, 32), 256, 0, stream>>>(
        x_ws, W1, b1, h_ws, M, DFF, 1024, nullptr, 0, nullptr, nullptr, nullptr, nullptr, nullptr);
    gemm_nt<0, 128, false, true><<<dim3(8, 32), 256, 0, stream>>>(
        h_ws, W2, b2, proj_ws, M, 1024, DFF, nullptr, 0, nullptr, nullptr, nullptr, nullptr, nullptr);
    ln_res<false, true><<<4096, 256, 0, stream>>>(proj_ws, x_ws, g2, be2, out);
  }
}

// Round 18
// 220.754 us; speedup vs baseline: 1.0572x; 1.0159x over previous
//
#include <hip/hip_runtime.h>
#include <hip/hip_bf16.h>

typedef __attribute__((ext_vector_type(4))) float f32x4;
typedef __attribute__((ext_vector_type(16))) float f32x16;
typedef __attribute__((ext_vector_type(8))) short s16x8;
typedef __attribute__((ext_vector_type(4))) short s16x4;
typedef __attribute__((ext_vector_type(2))) short s16x2;

typedef __attribute__((address_space(1))) const unsigned int guint;
typedef __attribute__((address_space(3))) unsigned int luint;

#define D_MODEL 1024
#define NHEAD 16
#define HEAD_DIM 64
#define DFF 4096
#define SEQ 2048
#define BATCH 2
#define QSCALE 0.18033688011112042f   // 0.125 * log2(e); attn uses exp2

__device__ __forceinline__ float b2f(short s) {
  union { unsigned int u; float f; } v;
  v.u = ((unsigned int)(unsigned short)s) << 16;
  return v.f;
}
__device__ __forceinline__ short f2b(float f) {
  __hip_bfloat16 h = __float2bfloat16(f);
  return *reinterpret_cast<short*>(&h);
}
__device__ __forceinline__ s16x8 cvt8(f32x4 a, f32x4 b) {
  s16x8 r;
  #pragma unroll
  for (int i = 0; i < 4; ++i) { r[i] = f2b(a[i]); r[i + 4] = f2b(b[i]); }
  return r;
}

// ---------------------------------------------------------------------------
// FFN GEMM v4 (r17, unchanged): 256x256 tile, BK=64, frag-complete kk-halves,
// 32x32x16 MFMA, counted vmcnt(2), 2 barriers/tile, 3-bit slot swizzle.
// MODE 0: relu(A@W^T+bias) (FFN1). MODE 1: split-K=4, bf16 partials (FFN2).
// ---------------------------------------------------------------------------
template<int MODE>
__global__ __launch_bounds__(512, 2)
void gemm_ff8(const short* __restrict__ A, const short* __restrict__ W,
              const float* __restrict__ bias, short* __restrict__ out,
              int N, int K,
              short* __restrict__ pB, short* __restrict__ pC,
              short* __restrict__ pD)
{
  __shared__ short Al[2][16384];
  __shared__ short Bl[2][16384];

  const int tid  = threadIdx.x;
  const int lane = tid & 63, wave = tid >> 6;
  const int l31 = lane & 31, hi = lane >> 5;
  const int wm = (wave >> 2) * 128;
  const int wn = (wave & 3) * 64;

  const int nwg = gridDim.x * gridDim.y;
  int lid = blockIdx.y * gridDim.x + blockIdx.x;
  if ((nwg & 7) == 0) lid = (lid & 7) * (nwg >> 3) + (lid >> 3);
  const int bn = lid % gridDim.x, bm = lid / gridDim.x;

  const int Keff = (MODE == 1) ? (K >> 2) : K;
  const int kOff = (MODE == 1) ? (int)blockIdx.z * Keff : 0;

  const int srow = tid >> 3;
  const int scol = (((tid & 7) ^ ((tid >> 3) & 7)) * 8);
  const short* gA = A + ((long)(bm * 256) + srow) * K + kOff + scol;
  const short* gW = W + ((long)(bn * 256) + srow) * K + kOff + scol;
  const long slotG = 64L * K;

  auto stage = [&](int buf, int slot, int k0) {
    luint* dA = (luint*)((short*)Al + buf * 16384 + slot * 4096 + wave * 512);
    luint* dB = (luint*)((short*)Bl + buf * 16384 + slot * 4096 + wave * 512);
    __builtin_amdgcn_global_load_lds((guint*)(gA + slot * slotG + k0), dA, 16, 0, 0);
    __builtin_amdgcn_global_load_lds((guint*)(gW + slot * slotG + k0), dB, 16, 0, 0);
  };

  const int sw = l31 & 7;

  f32x16 acc[4][2] = {};

  #pragma unroll
  for (int s = 0; s < 4; ++s) stage(0, s, 0);

  const int nt = Keff / 64;
  int cur = 0;
  for (int t = 0; t < nt; ++t) {
    const int k1 = (t + 1) * 64;
    if (t + 1 < nt) {
      stage(cur ^ 1, 0, k1);
      asm volatile("s_waitcnt vmcnt(2)" ::: "memory");
    } else {
      asm volatile("s_waitcnt vmcnt(0)" ::: "memory");
    }
    __builtin_amdgcn_s_barrier();
    __builtin_amdgcn_sched_barrier(0);

    const short* Abuf = (const short*)Al + cur * 16384;
    const short* Bbuf = (const short*)Bl + cur * 16384;

    #pragma unroll
    for (int half = 0; half < 2; ++half) {
      s16x8 av[4][2], bv2[2][2];
      #pragma unroll
      for (int mf = 0; mf < 4; ++mf) {
        const int row = wm + mf * 32 + l31;
        #pragma unroll
        for (int k2 = 0; k2 < 2; ++k2) {
          const int kk = half * 2 + k2;
          av[mf][k2] = *(const s16x8*)(Abuf + row * 64 + (((kk * 2 + hi) ^ sw) << 3));
        }
      }
      #pragma unroll
      for (int nf = 0; nf < 2; ++nf) {
        const int row = wn + nf * 32 + l31;
        #pragma unroll
        for (int k2 = 0; k2 < 2; ++k2) {
          const int kk = half * 2 + k2;
          bv2[nf][k2] = *(const s16x8*)(Bbuf + row * 64 + (((kk * 2 + hi) ^ sw) << 3));
        }
      }
      if (t + 1 < nt) {
        stage(cur ^ 1, half * 2 + 1, k1);
        if (half == 1) stage(cur ^ 1, 2, k1);
      }

      __builtin_amdgcn_s_setprio(1);
      #pragma unroll
      for (int k2 = 0; k2 < 2; ++k2)
        #pragma unroll
        for (int mf = 0; mf < 4; ++mf)
          #pragma unroll
          for (int nf = 0; nf < 2; ++nf)
            acc[mf][nf] = __builtin_amdgcn_mfma_f32_32x32x16_bf16(
                av[mf][k2], bv2[nf][k2], acc[mf][nf], 0, 0, 0);
      __builtin_amdgcn_s_setprio(0);
    }

    __builtin_amdgcn_sched_barrier(0);
    __builtin_amdgcn_s_barrier();
    cur ^= 1;
  }

  short* oz = out;
  if (MODE == 1) {
    const int z = blockIdx.z;
    oz = (z == 0) ? out : (z == 1) ? pB : (z == 2) ? pC : pD;
  }
  #pragma unroll
  for (int mf = 0; mf < 4; ++mf) {
    #pragma unroll
    for (int nf = 0; nf < 2; ++nf) {
      const int gn = bn * 256 + wn + nf * 32 + l31;
      const float bvv = (MODE == 0) ? bias[gn] : 0.f;
      #pragma unroll
      for (int reg = 0; reg < 16; ++reg) {
        const int gm = bm * 256 + wm + mf * 32 + (reg & 3) + 8 * (reg >> 2) + 4 * hi;
        float v = acc[mf][nf][reg] + bvv;
        if (MODE == 0) v = v > 0.f ? v : 0.f;
        oz[(long)gm * N + gn] = f2b(v);
      }
    }
  }
}

// ---------------------------------------------------------------------------
// NT GEMM r18: GLDS path upgraded to BK=64 + frag-complete reads (halve
// barriers, double MFMA/step — the r17 lever applied to projections).
// 3-bit slot swizzle (128B rows): phys slot = logical ^ (row&7), staging
// source col pre-swizzled within the 128B line. Counted vmcnt(6).
// MODE 0/1; 2/3/4 fallback (BK=32, unchanged); 6 split-K (Wo); 8 merged QKV.
// ---------------------------------------------------------------------------
template<int MODE, int BN, bool AF32, bool WF32>
__global__ __launch_bounds__(256, 3)
void gemm_nt(const void* __restrict__ Av, const void* __restrict__ Wv,
             const float* __restrict__ bias, short* __restrict__ out,
             int M, int N, int K,
             const int* __restrict__ idx, int R,
             const float* __restrict__ bias2, const float* __restrict__ bias3,
             short* __restrict__ pB, short* __restrict__ pC,
             short* __restrict__ pD)
{
  constexpr bool GLDS = (!AF32 && !WF32);
  constexpr int NI = BN / 32;

  const float* Af = (const float*)Av;
  const short* Ab = (const short*)Av;
  const float* Wf = (const float*)Wv;
  const short* Wb = (const short*)Wv;

  const int tid  = threadIdx.x;
  const int lane = tid & 63, wave = tid >> 6;
  const int g = lane >> 4, l15 = lane & 15;
  const int wm = (wave & 1) * 64, wn = (wave >> 1) * (BN / 2);

  const int nwg = gridDim.x * gridDim.y;
  int lid = blockIdx.y * gridDim.x + blockIdx.x;
  if ((nwg & 7) == 0) lid = (lid & 7) * (nwg >> 3) + (lid >> 3);
  const int bn = lid % gridDim.x;
  const int bm0 = lid / gridDim.x;

  int task = 0, bm = bm0, Mt = M;
  if (MODE == 8) {
    if (bm0 < 32)      { task = 0; bm = bm0;      Mt = M; }
    else if (bm0 < 39) { task = 1; bm = bm0 - 32; Mt = BATCH * R; }
    else               { task = 2; bm = bm0 - 39; Mt = BATCH * R; }
  }

  f32x4 acc[4][NI] = {};

  if constexpr (GLDS) {
    __shared__ short As[2][128][64];   // 32 KB
    __shared__ short Bs[2][BN][64];    // 16 KB @ BN=64

    const short* Wbase = Wb + ((MODE == 8) ? ((size_t)task << 20) : 0);
    const int nz   = (MODE == 6) ? gridDim.z : 1;
    const int Keff = K / nz;
    const int kOff = (MODE == 6) ? (int)blockIdx.z * Keff : 0;

    const int srow8 = lane >> 3;                 // 0..7
    const int scol  = ((lane & 7) ^ srow8) * 8;  // pre-swizzled source slot

    auto arow = [&](int r) -> long {
      const int gm = bm * 128 + r;
      const int am = gm < Mt ? gm : Mt - 1;
      if (MODE == 8 && task > 0) {
        const int b0 = am / R;
        return (long)(b0 * SEQ + idx[am - b0 * R]);
      }
      return am;
    };

    // A: wave covers rows [wave*32, wave*32+32), 4 issues of 8 rows
    const short* gAp[4];
    #pragma unroll
    for (int j = 0; j < 4; ++j)
      gAp[j] = Ab + arow(wave * 32 + j * 8 + srow8) * K + kOff + scol;
    // B: wave covers rows [wave*(BN/4), +BN/4), BN/32 issues of 8 rows
    constexpr int BI = BN / 32;
    const short* gBp[BI];
    #pragma unroll
    for (int j = 0; j < BI; ++j)
      gBp[j] = Wbase + ((long)bn * BN + wave * (BN / 4) + j * 8 + srow8) * K + kOff + scol;

    auto stage = [&](int buf, int k0) {
      #pragma unroll
      for (int j = 0; j < 4; ++j) {
        luint* d = (luint*)((short*)As + buf * 8192 + wave * 2048 + j * 512);
        __builtin_amdgcn_global_load_lds((guint*)(gAp[j] + k0), d, 16, 0, 0);
      }
      #pragma unroll
      for (int j = 0; j < BI; ++j) {
        luint* d = (luint*)((short*)Bs + buf * (BN * 64) + wave * (BN * 16) + j * 512);
        __builtin_amdgcn_global_load_lds((guint*)(gBp[j] + k0), d, 16, 0, 0);
      }
    };

    const int sw = l15 & 7;   // row&7 for all frag reads

    const int nt = Keff / 64;
    stage(0, 0);
    int cur = 0;
    for (int t = 0; t < nt; ++t) {
      if (t + 1 < nt) {
        stage(cur ^ 1, (t + 1) * 64);
        if constexpr (BN == 128) asm volatile("s_waitcnt vmcnt(8)" ::: "memory");
        else                     asm volatile("s_waitcnt vmcnt(6)" ::: "memory");
      } else {
        asm volatile("s_waitcnt vmcnt(0)" ::: "memory");
      }
      __builtin_amdgcn_s_barrier();
      __builtin_amdgcn_sched_barrier(0);

      // frag-complete: each frag read once (12 b128 @ BN=64)
      s16x8 af[4][2], bf[NI][2];
      #pragma unroll
      for (int mi = 0; mi < 4; ++mi)
        #pragma unroll
        for (int kk = 0; kk < 2; ++kk)
          af[mi][kk] = *(const s16x8*)&As[cur][wm + mi * 16 + l15][(((kk * 4 + g) ^ sw) << 3)];
      #pragma unroll
      for (int ni = 0; ni < NI; ++ni)
        #pragma unroll
        for (int kk = 0; kk < 2; ++kk)
          bf[ni][kk] = *(const s16x8*)&Bs[cur][wn + ni * 16 + l15][(((kk * 4 + g) ^ sw) << 3)];

      __builtin_amdgcn_s_setprio(1);
      #pragma unroll
      for (int kk = 0; kk < 2; ++kk)
        #pragma unroll
        for (int mi = 0; mi < 4; ++mi)
          #pragma unroll
          for (int ni = 0; ni < NI; ++ni)
            acc[mi][ni] = __builtin_amdgcn_mfma_f32_16x16x32_bf16(
                af[mi][kk], bf[ni][kk], acc[mi][ni], 0, 0, 0);
      __builtin_amdgcn_s_setprio(0);

      __builtin_amdgcn_sched_barrier(0);
      __builtin_amdgcn_s_barrier();
      cur ^= 1;
    }
  } else {
    __shared__ short As[128][40];
    __shared__ short Bs[128][40];
    const int r0 = tid >> 1, c0 = (tid & 1) * 16;
    const int gm0 = bm * 128 + r0;
    const int am0 = gm0 < M ? gm0 : M - 1;
    long aRow0;
    if (MODE == 3 || MODE == 4) {
      const int b0 = am0 / R;
      aRow0 = (long)(b0 * SEQ + idx[am0 - b0 * R]);
    } else {
      aRow0 = am0;
    }
    const long wRow0 = bn * 128 + r0;

    for (int k0 = 0; k0 < K; k0 += 32) {
      __syncthreads();
      if (AF32) {
        f32x4 a0 = *(const f32x4*)(Af + aRow0 * K + k0 + c0);
        f32x4 a1 = *(const f32x4*)(Af + aRow0 * K + k0 + c0 + 4);
        f32x4 a2 = *(const f32x4*)(Af + aRow0 * K + k0 + c0 + 8);
        f32x4 a3 = *(const f32x4*)(Af + aRow0 * K + k0 + c0 + 12);
        *(s16x8*)&As[r0][c0]     = cvt8(a0, a1);
        *(s16x8*)&As[r0][c0 + 8] = cvt8(a2, a3);
      } else {
        *(s16x8*)&As[r0][c0]     = *(const s16x8*)(Ab + aRow0 * K + k0 + c0);
        *(s16x8*)&As[r0][c0 + 8] = *(const s16x8*)(Ab + aRow0 * K + k0 + c0 + 8);
      }
      if (WF32) {
        f32x4 w0 = *(const f32x4*)(Wf + wRow0 * K + k0 + c0);
        f32x4 w1 = *(const f32x4*)(Wf + wRow0 * K + k0 + c0 + 4);
        f32x4 w2 = *(const f32x4*)(Wf + wRow0 * K + k0 + c0 + 8);
        f32x4 w3 = *(const f32x4*)(Wf + wRow0 * K + k0 + c0 + 12);
        *(s16x8*)&Bs[r0][c0]     = cvt8(w0, w1);
        *(s16x8*)&Bs[r0][c0 + 8] = cvt8(w2, w3);
      } else {
        *(s16x8*)&Bs[r0][c0]     = *(const s16x8*)(Wb + wRow0 * K + k0 + c0);
        *(s16x8*)&Bs[r0][c0 + 8] = *(const s16x8*)(Wb + wRow0 * K + k0 + c0 + 8);
      }
      __syncthreads();

      s16x8 af[4], bf4[4];
      #pragma unroll
      for (int mi = 0; mi < 4; ++mi)
        af[mi] = *(const s16x8*)&As[wm + mi * 16 + l15][g * 8];
      #pragma unroll
      for (int ni = 0; ni < 4; ++ni)
        bf4[ni] = *(const s16x8*)&Bs[wn + ni * 16 + l15][g * 8];
      #pragma unroll
      for (int mi = 0; mi < 4; ++mi)
        #pragma unroll
        for (int ni = 0; ni < 4; ++ni)
          acc[mi][ni % NI] = __builtin_amdgcn_mfma_f32_16x16x32_bf16(af[mi], bf4[ni], acc[mi][ni % NI], 0, 0, 0);
    }
  }

  short* outz = out;
  if (MODE == 6) {
    const int z = blockIdx.z;
    outz = (z == 0) ? out : (z == 1) ? pB : (z == 2) ? pC : pD;
  }

  #pragma unroll
  for (int mi = 0; mi < 4; ++mi) {
    #pragma unroll
    for (int ni = 0; ni < NI; ++ni) {
      const int gn = bn * BN + wn + ni * 16 + l15;
      float bv;
      if (MODE == 6)      bv = 0.f;
      else if (MODE == 8) bv = (task == 0) ? bias[gn] : (task == 1) ? bias2[gn] : bias3[gn];
      else                bv = bias[gn];
      #pragma unroll
      for (int r = 0; r < 4; ++r) {
        const int gm = bm * 128 + wm + mi * 16 + g * 4 + r;
        if (MODE == 8) { if (gm >= Mt) continue; }
        else           { if (gm >= M)  continue; }
        float v = acc[mi][ni][r] + bv;
        if (MODE == 1) v = v > 0.f ? v : 0.f;
        if (MODE == 2) v *= QSCALE;
        if (MODE == 0 || MODE == 1) {
          out[(long)gm * N + gn] = f2b(v);
        } else if (MODE == 2) {
          const int b = gm >> 11, s = gm & (SEQ - 1);
          const int h = gn >> 6, d = gn & 63;
          out[(((long)(b * NHEAD + h)) * SEQ + s) * 64 + d] = f2b(v);
        } else if (MODE == 3) {
          const int b = gm / R, s = idx[gm - b * R];
          const int h = gn >> 6, d = gn & 63;
          out[(((long)(b * NHEAD + h)) * SEQ + s) * 64 + d] = f2b(v);
        } else if (MODE == 4) {
          const int b = gm / R, s = idx[gm - b * R];
          const int h = gn >> 6, d = gn & 63;
          out[(((long)(b * NHEAD + h)) * 64 + d) * SEQ + s] = f2b(v);
        } else if (MODE == 6) {
          outz[(long)gm * N + gn] = f2b(v);
        } else {  // MODE 8
          const int h = gn >> 6, d = gn & 63;
          if (task == 0) {
            const int b = gm >> 11, s = gm & (SEQ - 1);
            out[(((long)(b * NHEAD + h)) * SEQ + s) * 64 + d] = f2b(v * QSCALE);
          } else if (task == 1) {
            const int b = gm / R, s = idx[gm - b * R];
            (out + (1L << 22))[(((long)(b * NHEAD + h)) * SEQ + s) * 64 + d] = f2b(v);
          } else {
            const int b = gm / R, s = idx[gm - b * R];
            (out + (1L << 23))[(((long)(b * NHEAD + h)) * 64 + d) * SEQ + s] = f2b(v);
          }
        }
      }
    }
  }
}

// ---------------------------------------------------------------------------
// Flash attention fwd v4 (unchanged): swapped QK^T, permlane P, pre-swizzled
// glds staging, exp2, ones-MFMA row-sum, counted-vmcnt raw-barrier loop.
// ---------------------------------------------------------------------------
__global__ __launch_bounds__(256, 2)
void attn_fwd(const short* __restrict__ Q, const short* __restrict__ Kf,
              const short* __restrict__ Vt, short* __restrict__ out)
{
  __shared__ short Kl[2][64][64];
  __shared__ short Vl[2][64][64];

  const int tid  = threadIdx.x;
  const int lane = tid & 63, w = tid >> 6;
  const int g = lane >> 4, l15 = lane & 15;
  const int bh = blockIdx.x;
  const int qt = blockIdx.y;
  const int b  = bh >> 4, h = bh & 15;

  const long base = (long)bh * SEQ * 64;
  const int  q0   = qt * 128 + w * 32;

  s16x8 qf[2][2];
  #pragma unroll
  for (int mi = 0; mi < 2; ++mi)
    #pragma unroll
    for (int c = 0; c < 2; ++c)
      qf[mi][c] = *(const s16x8*)(Q + base + (long)(q0 + mi * 16 + l15) * 64 + c * 32 + g * 8);

  f32x4 o[2][4] = {};
  f32x4 os[2] = {};

  s16x8 ones;
  #pragma unroll
  for (int j = 0; j < 8; ++j) ones[j] = (short)0x3F80;

  auto ldsw = [](short (*buf)[64], int row, int slot) -> short* {
    return (short*)((char*)&buf[0][0] + row * 128 + ((slot ^ (row & 7)) << 4));
  };

  const int bo0 = w * 2048 + lane * 16;
  const int bo1 = bo0 + 1024;
  const int row0 = bo0 >> 7, ss0 = (((bo0 >> 4) & 7) ^ (row0 & 7));
  const int row1 = bo1 >> 7, ss1 = (((bo1 >> 4) & 7) ^ (row1 & 7));
  const short* gK0 = Kf + base + row0 * 64 + ss0 * 8;
  const short* gK1 = Kf + base + row1 * 64 + ss1 * 8;
  const short* gV0 = Vt + base + (long)row0 * SEQ + ss0 * 8;
  const short* gV1 = Vt + base + (long)row1 * SEQ + ss1 * 8;

  auto stage = [&](int buf, int t) {
    char* kb8 = (char*)&Kl[buf][0][0] + w * 2048;
    char* vb8 = (char*)&Vl[buf][0][0] + w * 2048;
    __builtin_amdgcn_global_load_lds((guint*)(gK0 + t * 4096), (luint*)kb8, 16, 0, 0);
    __builtin_amdgcn_global_load_lds((guint*)(gK1 + t * 4096), (luint*)(kb8 + 1024), 16, 0, 0);
    __builtin_amdgcn_global_load_lds((guint*)(gV0 + t * 64), (luint*)vb8, 16, 0, 0);
    __builtin_amdgcn_global_load_lds((guint*)(gV1 + t * 64), (luint*)(vb8 + 1024), 16, 0, 0);
  };

  stage(0, 0);
  int cur = 0;
  for (int t = 0; t < SEQ / 64; ++t) {
    if (t + 1 < SEQ / 64) {
      stage(cur ^ 1, t + 1);
      asm volatile("s_waitcnt vmcnt(4)" ::: "memory");
    } else {
      asm volatile("s_waitcnt vmcnt(0)" ::: "memory");
    }
    __builtin_amdgcn_s_barrier();
    __builtin_amdgcn_sched_barrier(0);

    f32x4 sc[2][4] = {};
    __builtin_amdgcn_s_setprio(1);
    #pragma unroll
    for (int c = 0; c < 2; ++c)
      #pragma unroll
      for (int n = 0; n < 4; ++n) {
        s16x8 kb = *(const s16x8*)ldsw(Kl[cur], n * 16 + l15, c * 4 + g);
        sc[0][n] = __builtin_amdgcn_mfma_f32_16x16x32_bf16(kb, qf[0][c], sc[0][n], 0, 0, 0);
        sc[1][n] = __builtin_amdgcn_mfma_f32_16x16x32_bf16(kb, qf[1][c], sc[1][n], 0, 0, 0);
      }
    __builtin_amdgcn_s_setprio(0);

    s16x8 pa[2][2];
    #pragma unroll
    for (int mi = 0; mi < 2; ++mi) {
      #pragma unroll
      for (int n = 0; n < 4; ++n)
        #pragma unroll
        for (int r = 0; r < 4; ++r) {
          float e;
          asm("v_exp_f32 %0, %1" : "=v"(e) : "v"(sc[mi][n][r]));
          sc[mi][n][r] = e;
        }
      unsigned int wpk[4][2];
      #pragma unroll
      for (int n = 0; n < 4; ++n)
        #pragma unroll
        for (int p = 0; p < 2; ++p)
          asm("v_cvt_pk_bf16_f32 %0, %1, %2"
              : "=v"(wpk[n][p]) : "v"(sc[mi][n][2 * p]), "v"(sc[mi][n][2 * p + 1]));
      #pragma unroll
      for (int c = 0; c < 2; ++c) {
        union { s16x8 v; unsigned int u[4]; } pu;
        #pragma unroll
        for (int p = 0; p < 2; ++p) {
          unsigned int a = wpk[2 * c][p], bb = wpk[2 * c + 1][p];
          asm volatile("v_permlane32_swap_b32 %0, %1" : "+v"(a), "+v"(bb));
          asm volatile("v_permlane16_swap_b32 %0, %1" : "+v"(a), "+v"(bb));
          pu.u[p]     = a;
          pu.u[2 + p] = bb;
        }
        pa[mi][c] = pu.v;
      }
    }

    __builtin_amdgcn_s_setprio(1);
    #pragma unroll
    for (int dt = 0; dt < 4; ++dt)
      #pragma unroll
      for (int c = 0; c < 2; ++c) {
        s16x8 vb = *(const s16x8*)ldsw(Vl[cur], dt * 16 + l15, c * 4 + g);
        o[0][dt] = __builtin_amdgcn_mfma_f32_16x16x32_bf16(pa[0][c], vb, o[0][dt], 0, 0, 0);
        o[1][dt] = __builtin_amdgcn_mfma_f32_16x16x32_bf16(pa[1][c], vb, o[1][dt], 0, 0, 0);
      }
    #pragma unroll
    for (int mi = 0; mi < 2; ++mi)
      #pragma unroll
      for (int c = 0; c < 2; ++c)
        os[mi] = __builtin_amdgcn_mfma_f32_16x16x32_bf16(pa[mi][c], ones, os[mi], 0, 0, 0);
    __builtin_amdgcn_s_setprio(0);

    __builtin_amdgcn_sched_barrier(0);
    __builtin_amdgcn_s_barrier();
    cur ^= 1;
  }

  float inv[2][4];
  #pragma unroll
  for (int mi = 0; mi < 2; ++mi)
    #pragma unroll
    for (int r = 0; r < 4; ++r)
      inv[mi][r] = 1.0f / os[mi][r];

  #pragma unroll
  for (int mi = 0; mi < 2; ++mi)
    #pragma unroll
    for (int dt = 0; dt < 4; ++dt)
      #pragma unroll
      for (int r = 0; r < 4; ++r) {
        const int q   = q0 + mi * 16 + g * 4 + r;
        const int col = h * 64 + dt * 16 + l15;
        out[((long)(b * SEQ + q)) * D_MODEL + col] = f2b(o[mi][dt][r] * inv[mi][r]);
      }
}

// ---------------------------------------------------------------------------
// Residual + LN with fused 2-way split-K reduce
// ---------------------------------------------------------------------------
template<bool RES_F32, bool OUT_F32>
__global__ __launch_bounds__(256, 4)
void ln_ff2(const short* __restrict__ p0, const short* __restrict__ p1,
            const float* __restrict__ bias, const void* __restrict__ resv,
            const float* __restrict__ g, const float* __restrict__ beta,
            void* __restrict__ outv)
{
  __shared__ float red[8];
  const int row = blockIdx.x;
  const int tid = threadIdx.x;
  const int lane = tid & 63, w = tid >> 6;

  s16x4 v0 = *(const s16x4*)(p0 + (long)row * D_MODEL + tid * 4);
  s16x4 v1 = *(const s16x4*)(p1 + (long)row * D_MODEL + tid * 4);
  f32x4 vb = *(const f32x4*)(bias + tid * 4);
  float x[4];
  if (RES_F32) {
    f32x4 vr = *(const f32x4*)((const float*)resv + (long)row * D_MODEL + tid * 4);
    #pragma unroll
    for (int i = 0; i < 4; ++i) x[i] = vr[i] + b2f(v0[i]) + b2f(v1[i]) + vb[i];
  } else {
    s16x4 vr = *(const s16x4*)((const short*)resv + (long)row * D_MODEL + tid * 4);
    #pragma unroll
    for (int i = 0; i < 4; ++i) x[i] = b2f(vr[i]) + b2f(v0[i]) + b2f(v1[i]) + vb[i];
  }

  float sum = x[0] + x[1] + x[2] + x[3];
  #pragma unroll
  for (int msk = 32; msk >= 1; msk >>= 1) sum += __shfl_xor(sum, msk, 64);
  if (lane == 0) red[w] = sum;
  __syncthreads();
  sum = red[0] + red[1] + red[2] + red[3];
  const float mu = sum * (1.f / D_MODEL);

  float sq = 0.f;
  #pragma unroll
  for (int i = 0; i < 4; ++i) { float d = x[i] - mu; sq += d * d; }
  #pragma unroll
  for (int msk = 32; msk >= 1; msk >>= 1) sq += __shfl_xor(sq, msk, 64);
  if (lane == 0) red[4 + w] = sq;
  __syncthreads();
  sq = red[4] + red[5] + red[6] + red[7];
  const float rs = rsqrtf(sq * (1.f / D_MODEL) + 1e-5f);

  if (OUT_F32) {
    f32x4 ov;
    #pragma unroll
    for (int i = 0; i < 4; ++i) {
      const int c = tid * 4 + i;
      ov[i] = (x[i] - mu) * rs * g[c] + beta[c];
    }
    *(f32x4*)((float*)outv + (long)row * D_MODEL + tid * 4) = ov;
  } else {
    s16x4 ov;
    #pragma unroll
    for (int i = 0; i < 4; ++i) {
      const int c = tid * 4 + i;
      ov[i] = f2b((x[i] - mu) * rs * g[c] + beta[c]);
    }
    *(s16x4*)((short*)outv + (long)row * D_MODEL + tid * 4) = ov;
  }
}

// ---------------------------------------------------------------------------
// Final LN with fused 4-way split-K reduce -> f32 out
// ---------------------------------------------------------------------------
__global__ __launch_bounds__(256, 4)
void ln_ff4(const short* __restrict__ p0, const short* __restrict__ p1,
            const short* __restrict__ p2, const short* __restrict__ p3,
            const float* __restrict__ bias, const short* __restrict__ xres,
            const float* __restrict__ g, const float* __restrict__ beta,
            float* __restrict__ outv)
{
  __shared__ float red[8];
  const int row = blockIdx.x;
  const int tid = threadIdx.x;
  const int lane = tid & 63, w = tid >> 6;

  s16x4 v0 = *(const s16x4*)(p0 + (long)row * D_MODEL + tid * 4);
  s16x4 v1 = *(const s16x4*)(p1 + (long)row * D_MODEL + tid * 4);
  s16x4 v2 = *(const s16x4*)(p2 + (long)row * D_MODEL + tid * 4);
  s16x4 v3 = *(const s16x4*)(p3 + (long)row * D_MODEL + tid * 4);
  s16x4 vx = *(const s16x4*)(xres + (long)row * D_MODEL + tid * 4);
  f32x4 vb = *(const f32x4*)(bias + tid * 4);
  float x[4];
  #pragma unroll
  for (int i = 0; i < 4; ++i)
    x[i] = b2f(vx[i]) + b2f(v0[i]) + b2f(v1[i]) + b2f(v2[i]) + b2f(v3[i]) + vb[i];

  float sum = x[0] + x[1] + x[2] + x[3];
  #pragma unroll
  for (int msk = 32; msk >= 1; msk >>= 1) sum += __shfl_xor(sum, msk, 64);
  if (lane == 0) red[w] = sum;
  __syncthreads();
  sum = red[0] + red[1] + red[2] + red[3];
  const float mu = sum * (1.f / D_MODEL);

  float sq = 0.f;
  #pragma unroll
  for (int i = 0; i < 4; ++i) { float d = x[i] - mu; sq += d * d; }
  #pragma unroll
  for (int msk = 32; msk >= 1; msk >>= 1) sq += __shfl_xor(sq, msk, 64);
  if (lane == 0) red[4 + w] = sq;
  __syncthreads();
  sq = red[4] + red[5] + red[6] + red[7];
  const float rs = rsqrtf(sq * (1.f / D_MODEL) + 1e-5f);

  f32x4 ov;
  #pragma unroll
  for (int i = 0; i < 4; ++i) {
    const int c = tid * 4 + i;
    ov[i] = (x[i] - mu) * rs * g[c] + beta[c];
  }
  *(f32x4*)(outv + (long)row * D_MODEL + tid * 4) = ov;
}

// ---------------------------------------------------------------------------
// Residual + LayerNorm (fallback path)
// ---------------------------------------------------------------------------
template<bool RES_F32, bool OUT_F32>
__global__ __launch_bounds__(256, 4)
void ln_res(const short* __restrict__ a, const void* __restrict__ resv,
            const float* __restrict__ g, const float* __restrict__ beta,
            void* __restrict__ outv)
{
  __shared__ float red[8];
  const int row = blockIdx.x;
  const int tid = threadIdx.x;
  const int lane = tid & 63, w = tid >> 6;

  s16x4 va = *(const s16x4*)(a + (long)row * D_MODEL + tid * 4);
  float x[4];
  if (RES_F32) {
    f32x4 vr = *(const f32x4*)((const float*)resv + (long)row * D_MODEL + tid * 4);
    #pragma unroll
    for (int i = 0; i < 4; ++i) x[i] = b2f(va[i]) + vr[i];
  } else {
    s16x4 vr = *(const s16x4*)((const short*)resv + (long)row * D_MODEL + tid * 4);
    #pragma unroll
    for (int i = 0; i < 4; ++i) x[i] = b2f(va[i]) + b2f(vr[i]);
  }
  float sum = x[0] + x[1] + x[2] + x[3];
  #pragma unroll
  for (int msk = 32; msk >= 1; msk >>= 1) sum += __shfl_xor(sum, msk, 64);
  if (lane == 0) red[w] = sum;
  __syncthreads();
  sum = red[0] + red[1] + red[2] + red[3];
  const float mu = sum * (1.f / D_MODEL);

  float sq = 0.f;
  #pragma unroll
  for (int i = 0; i < 4; ++i) { float d = x[i] - mu; sq += d * d; }
  #pragma unroll
  for (int msk = 32; msk >= 1; msk >>= 1) sq += __shfl_xor(sq, msk, 64);
  if (lane == 0) red[4 + w] = sq;
  __syncthreads();
  sq = red[4] + red[5] + red[6] + red[7];
  const float rs = rsqrtf(sq * (1.f / D_MODEL) + 1e-5f);

  if (OUT_F32) {
    f32x4 ov;
    #pragma unroll
    for (int i = 0; i < 4; ++i) {
      const int c = tid * 4 + i;
      ov[i] = (x[i] - mu) * rs * g[c] + beta[c];
    }
    *(f32x4*)((float*)outv + (long)row * D_MODEL + tid * 4) = ov;
  } else {
    s16x4 ov;
    #pragma unroll
    for (int i = 0; i < 4; ++i) {
      const int c = tid * 4 + i;
      ov[i] = f2b((x[i] - mu) * rs * g[c] + beta[c]);
    }
    *(s16x4*)((short*)outv + (long)row * D_MODEL + tid * 4) = ov;
  }
}

// ---------------------------------------------------------------------------
// Merged f32->bf16 conversions + cached-V transpose
// ---------------------------------------------------------------------------
__global__ void cvt_all(const float* __restrict__ ck, const float* __restrict__ cv,
                        const float* __restrict__ src,
                        const float* __restrict__ Wq, const float* __restrict__ Wk,
                        const float* __restrict__ Wv, const float* __restrict__ Wo,
                        const float* __restrict__ W1, const float* __restrict__ W2,
                        short* __restrict__ k_ws, short* __restrict__ v_ws,
                        short* __restrict__ srcb,
                        short* __restrict__ Wqb, short* __restrict__ W1b,
                        short* __restrict__ W2b)
{
  for (int i = blockIdx.x * blockDim.x + threadIdx.x; i < 5767168;
       i += gridDim.x * blockDim.x) {
    if (i >= 5242880) {               // cached V -> V^T, 8-elem chunks
      const int j = i - 5242880;
      const int bh = j >> 14;
      const int rem = j & 16383;
      const int d = rem & 63;
      const int s0 = (rem >> 6) << 3;
      s16x8 r;
      #pragma unroll
      for (int k = 0; k < 8; ++k)
        r[k] = f2b(cv[((long)bh * SEQ + s0 + k) * 64 + d]);
      *(s16x8*)(v_ws + ((long)bh * 64 + d) * SEQ + s0) = r;
      continue;
    }
    const float* s; short* d; int li;
    if      (i < 1048576) { s = ck;  d = k_ws;           li = i; }
    else if (i < 2097152) { s = src; d = srcb;           li = i - 1048576; }
    else if (i < 2359296) { s = Wq;  d = Wqb;            li = i - 2097152; }
    else if (i < 2621440) { s = Wk;  d = Wqb + 1048576;  li = i - 2359296; }
    else if (i < 2883584) { s = Wv;  d = Wqb + 2097152;  li = i - 2621440; }
    else if (i < 3145728) { s = Wo;  d = Wqb + 3145728;  li = i - 2883584; }
    else if (i < 4194304) { s = W1;  d = W1b;            li = i - 3145728; }
    else                  { s = W2;  d = W2b;            li = i - 4194304; }
    f32x4 v = *(const f32x4*)(s + (long)li * 4);
    s16x4 r;
    #pragma unroll
    for (int j = 0; j < 4; ++j) r[j] = f2b(v[j]);
    *(s16x4*)(d + (long)li * 4) = r;
  }
}

// cached V (B,H,S,64) f32 -> V^T (B,H,64,S) bf16  (fallback path)
__global__ void cvt_v_t(const float* __restrict__ in, short* __restrict__ out)
{
  const int c2 = blockIdx.x * blockDim.x + threadIdx.x;
  const int bh = c2 >> 14;
  const int rem = c2 & 16383;
  const int d = rem & 63;
  const int s0 = (rem >> 6) << 3;
  s16x8 r;
  #pragma unroll
  for (int j = 0; j < 8; ++j)
    r[j] = f2b(in[((long)bh * SEQ + s0 + j) * 64 + d]);
  *(s16x8*)(out + ((long)bh * 64 + d) * SEQ + s0) = r;
}

// f32 -> bf16 (fallback path)
__global__ void cvt_f32_bf16(const f32x4* __restrict__ in, s16x4* __restrict__ out, int n4)
{
  for (int i = blockIdx.x * blockDim.x + threadIdx.x; i < n4; i += gridDim.x * blockDim.x) {
    f32x4 v = in[i];
    s16x4 r;
    #pragma unroll
    for (int j = 0; j < 4; ++j) r[j] = f2b(v[j]);
    out[i] = r;
  }
}

extern "C" void kernel_launch(void* const* d_in, const int* in_sizes, int n_in,
                              void* d_out, int out_size, void* d_ws, size_t ws_size,
                              hipStream_t stream)
{
  const float* src = (const float*)d_in[0];
  const int*   idx = (const int*)  d_in[1];
  const float* ck  = (const float*)d_in[2];
  const float* cv  = (const float*)d_in[3];
  const float* Wq  = (const float*)d_in[4];
  const float* bq  = (const float*)d_in[5];
  const float* Wk  = (const float*)d_in[6];
  const float* bk  = (const float*)d_in[7];
  const float* Wv  = (const float*)d_in[8];
  const float* bv  = (const float*)d_in[9];
  const float* Wo  = (const float*)d_in[10];
  const float* bo  = (const float*)d_in[11];
  const float* W1  = (const float*)d_in[12];
  const float* b1  = (const float*)d_in[13];
  const float* W2  = (const float*)d_in[14];
  const float* b2  = (const float*)d_in[15];
  const float* g1  = (const float*)d_in[16];
  const float* be1 = (const float*)d_in[17];
  const float* g2  = (const float*)d_in[18];
  const float* be2 = (const float*)d_in[19];
  float* out = (float*)d_out;

  char* ws = (char*)d_ws;
  const size_t SZ = (size_t)4096 * 1024 * 2;  // 8 MB = 1<<22 shorts
  short* x_ws    = (short*)(ws);              // region 0
  short* proj_ws = (short*)(ws + SZ);         // region 1: Wo p0 / FFN2 p0
  short* q_ws    = (short*)(ws + 2 * SZ);     // region 2: Q / Wo p1
  short* k_ws    = (short*)(ws + 3 * SZ);
  short* v_ws    = (short*)(ws + 4 * SZ);
  short* attn_ws = (short*)(ws + 5 * SZ);
  short* h_ws    = (short*)(ws + 2 * SZ);     // 32MB (2..5), after attn phase
  short* W1b     = (short*)(ws + 6 * SZ);     // FFN2 p1 (after FFN1)
  short* W2b     = (short*)(ws + 7 * SZ);
  short* srcb    = (short*)(ws + 8 * SZ);     // FFN2 p2
  short* Wqb     = (short*)(ws + 9 * SZ);     // proj weights; FFN2 p3
  const bool big = ws_size >= 10 * SZ;        // 80 MB

  const int M = BATCH * SEQ;      // 4096
  const int R = 409;
  const int Mr = BATCH * R;       // 818
  const int nkv4 = BATCH * NHEAD * SEQ * HEAD_DIM / 4;

  if (big) {
    cvt_all<<<2048, 256, 0, stream>>>(ck, cv, src, Wq, Wk, Wv, Wo, W1, W2,
                                      k_ws, v_ws, srcb, Wqb, W1b, W2b);
    // merged Q/K/V projections, BN=64, BK=64 frag-complete -> 736 blocks
    gemm_nt<8, 64, false, false><<<dim3(16, 46), 256, 0, stream>>>(
        srcb, Wqb, bq, q_ws, M, 1024, 1024, idx, R, bk, bv, nullptr, nullptr, nullptr);
    attn_fwd<<<dim3(BATCH * NHEAD, SEQ / 128), 256, 0, stream>>>(q_ws, k_ws, v_ws, attn_ws);
    // Wo projection, split-K=2, BN=64 -> 1024 blocks
    gemm_nt<6, 64, false, false><<<dim3(16, 32, 2), 256, 0, stream>>>(
        attn_ws, Wqb + 3145728, nullptr, proj_ws, M, 1024, 1024, nullptr, 0,
        nullptr, nullptr, q_ws, nullptr, nullptr);
    ln_ff2<true, false><<<4096, 256, 0, stream>>>(proj_ws, q_ws, bo, src, g1, be1, x_ws);
    // FFN1: 256x256, frag-complete kk-halves, grid 16x16 = 256 blocks
    gemm_ff8<0><<<dim3(16, 16), 512, 0, stream>>>(
        x_ws, W1b, b1, h_ws, DFF, 1024, nullptr, nullptr, nullptr);
    // FFN2: split-K=4 -> partials proj_ws / W1b / srcb / Wqb
    gemm_ff8<1><<<dim3(4, 16, 4), 512, 0, stream>>>(
        h_ws, W2b, nullptr, proj_ws, 1024, 4096, W1b, srcb, Wqb);
    ln_ff4<<<4096, 256, 0, stream>>>(proj_ws, W1b, srcb, Wqb, b2, x_ws, g2, be2, out);
  } else {
    cvt_f32_bf16<<<2048, 256, 0, stream>>>((const f32x4*)ck, (s16x4*)k_ws, nkv4);
    cvt_v_t<<<2048, 256, 0, stream>>>(cv, v_ws);
    gemm_nt<2, 128, true, true><<<dim3(8, 32), 256, 0, stream>>>(
        src, Wq, bq, q_ws, M, 1024, 1024, nullptr, 0, nullptr, nullptr, nullptr, nullptr, nullptr);
    gemm_nt<3, 128, true, true><<<dim3(8, 7), 256, 0, stream>>>(
        src, Wk, bk, k_ws, Mr, 1024, 1024, idx, R, nullptr, nullptr, nullptr, nullptr, nullptr);
    gemm_nt<4, 128, true, true><<<dim3(8, 7), 256, 0, stream>>>(
        src, Wv, bv, v_ws, Mr, 1024, 1024, idx, R, nullptr, nullptr, nullptr, nullptr, nullptr);
    attn_fwd<<<dim3(BATCH * NHEAD, SEQ / 128), 256, 0, stream>>>(q_ws, k_ws, v_ws, attn_ws);
    gemm_nt<0, 128, false, true><<<dim3(8, 32), 256, 0, stream>>>(
        attn_ws, Wo, bo, proj_ws, M, 1024, 1024, nullptr, 0, nullptr, nullptr, nullptr, nullptr, nullptr);
    ln_res<true, false><<<4096, 256, 0, stream>>>(proj_ws, src, g1, be1, x_ws);
    gemm_nt<1, 128, false, true><<<dim3(32, 32), 256, 0, stream>>>(
        x_ws, W1, b1, h_ws, M, DFF, 1024, nullptr, 0, nullptr, nullptr, nullptr, nullptr, nullptr);
    gemm_nt<0, 128, false, true><<<dim3(8, 32), 256, 0, stream>>>(
        h_ws, W2, b2, proj_ws, M, 1024, DFF, nullptr, 0, nullptr, nullptr, nullptr, nullptr, nullptr);
    ln_res<false, true><<<4096, 256, 0, stream>>>(proj_ws, x_ws, g2, be2, out);
  }
}